// Round 7
// baseline (508.133 us; speedup 1.0000x reference)
//
#include <hip/hip_runtime.h>

typedef unsigned short u16;
typedef unsigned int u32;
typedef __attribute__((ext_vector_type(8))) short short8v;
typedef __attribute__((ext_vector_type(4))) float float4v;

__device__ __forceinline__ float sigm(float x) { return 1.0f / (1.0f + __expf(-x)); }
__device__ __forceinline__ u16 f2bf(float f) {
  u32 u = __float_as_uint(f);
  u32 r = (u + 0x7fffu + ((u >> 16) & 1u)) >> 16;
  return (u16)r;
}
__device__ __forceinline__ float bf2f(u16 w) { return __uint_as_float(((u32)w) << 16); }

__global__ void k_cnt(const int* __restrict__ dst, int* __restrict__ cnt, int E) {
  int e = blockIdx.x * blockDim.x + threadIdx.x;
  if (e < E) atomicAdd(&cnt[dst[e]], 1);
}

// --- parallel scan: scan1 block sums -> scan2 scan of ~98 sums -> scan3 local scan ---
__global__ void k_scan1(const int* __restrict__ cnt, int* __restrict__ bsum, int N) {
  __shared__ int ws[4];
  int t = threadIdx.x;
  int i = blockIdx.x * 256 + t;
  int v = (i < N) ? cnt[i] : 0;
  int s = v;
  for (int off = 1; off < 64; off <<= 1) s += __shfl_xor(s, off);
  int wid = t >> 6, lane = t & 63;
  if (lane == 0) ws[wid] = s;
  __syncthreads();
  if (t == 0) bsum[blockIdx.x] = ws[0] + ws[1] + ws[2] + ws[3];
}

__global__ void k_scan2(int* __restrict__ bsum, int* __restrict__ row, int nb, int N) {
  __shared__ int s[256];
  int t = threadIdx.x;
  if (t < nb) s[t] = bsum[t];
  __syncthreads();
  if (t == 0) {
    int run = 0;
    for (int i = 0; i < nb; ++i) { int x = s[i]; s[i] = run; run += x; }
    row[N] = run;
  }
  __syncthreads();
  if (t < nb) bsum[t] = s[t];
}

__global__ void k_scan3(const int* __restrict__ cnt, const int* __restrict__ bsum,
                        int* __restrict__ row, int* __restrict__ cursor, int N) {
  __shared__ int ws[4];
  int t = threadIdx.x;
  int i = blockIdx.x * 256 + t;
  int v = (i < N) ? cnt[i] : 0;
  int lane = t & 63, wid = t >> 6;
  int incl = v;
  for (int off = 1; off < 64; off <<= 1) {
    int u = __shfl_up(incl, off);
    if (lane >= off) incl += u;
  }
  if (lane == 63) ws[wid] = incl;
  __syncthreads();
  int woff = bsum[blockIdx.x];
  for (int w = 0; w < wid; ++w) woff += ws[w];
  int excl = woff + incl - v;
  if (i < N) { row[i] = excl; cursor[i] = excl; }
}

// pos[e] = CSR slot of edge e (counting sort position among same-dst edges)
__global__ void k_pos(const int* __restrict__ dst, int* __restrict__ cursor,
                      int* __restrict__ pos, int E) {
  int e = blockIdx.x * blockDim.x + threadIdx.x;
  if (e < E) pos[e] = atomicAdd(&cursor[dst[e]], 1);
}

// Fused prep, r25: node MLP + W_e2 pack + GRU packs + W_l1 pack + EDGE MLP
// (edge MLP rewritten 1-thread-per-edge; kills the 25000-block dispatch)
__global__ void k_prep_all(
    const float* __restrict__ x, const float* __restrict__ Wn,
    const float* __restrict__ bn, float* __restrict__ h, int N, int nbNode,
    const float* __restrict__ W2, u16* __restrict__ Bph, int nbPack,
    const float* __restrict__ Wih, const float* __restrict__ Whh,
    u16* __restrict__ WpI, u16* __restrict__ WpH, int nbWtf,
    const float* __restrict__ Wl1, u16* __restrict__ Wp1, int nbWl1,
    const float* __restrict__ ea_in, const float* __restrict__ Wea,
    const float* __restrict__ bea, const float* __restrict__ We1,
    const float* __restrict__ be1, u16* __restrict__ Ahi, int E) {
  int b = blockIdx.x;
  if (b < nbNode) {
    int tid = b * 256 + threadIdx.x;
    if (tid >= N * 64) return;
    int n = tid >> 6, f = tid & 63;
    float acc = bn[f];
    for (int k = 0; k < 8; ++k) acc += x[(size_t)n * 8 + k] * Wn[k * 64 + f];
    h[tid] = fmaxf(acc, 0.0f);
  } else if (b < nbNode + nbPack) {
    int tid = (b - nbNode) * 256 + threadIdx.x;
    if (tid >= 128 * 4096) return;
    int j = tid & 7;
    int lane = (tid >> 3) & 63;
    int nt = (tid >> 9) & 3;
    int ks = (tid >> 11) & 3;
    int d = tid >> 13;
    int c = lane & 15, q = lane >> 4;
    int k = ks * 32 + q * 8 + j;
    int n = d * 64 + nt * 16 + c;
    Bph[tid] = f2bf(W2[(size_t)k * 4096 + n]);
  } else if (b < nbNode + nbPack + nbWtf) {
    int tid = (b - nbNode - nbPack) * 256 + threadIdx.x;
    if (tid >= 2 * 12288) return;
    int w = tid / 12288;
    int r = tid - w * 12288;
    int jj = r & 7;
    int lane = (r >> 3) & 63;
    int t = r >> 9;
    int nt = t % 12, ks = t / 12;
    int c = lane & 15, q = lane >> 4;
    int j = nt * 16 + c;
    int k = ks * 32 + q * 8 + jj;
    const float* W = w ? Whh : Wih;
    u16* Wp = w ? WpH : WpI;
    Wp[r] = f2bf(W[j * 64 + k]);
  } else if (b < nbNode + nbPack + nbWtf + nbWl1) {
    int tid = (b - nbNode - nbPack - nbWtf) * 256 + threadIdx.x;
    if (tid >= 3 * 8 * 64 * 8) return;
    int j = tid & 7;
    int lane = (tid >> 3) & 63;
    int nt = (tid >> 9) & 7;
    int ks = tid >> 12;
    int c = lane & 15, q = lane >> 4;
    int k = ks * 32 + q * 8 + j;
    int n = nt * 16 + c;
    Wp1[tid] = f2bf((k < 72) ? Wl1[k * 128 + n] : 0.0f);
  } else {
    // edge MLP: one thread per edge
    int e = (b - nbNode - nbPack - nbWtf - nbWl1) * 256 + threadIdx.x;
    if (e >= E) return;
    float att[19];
#pragma unroll
    for (int k = 0; k < 19; ++k) att[k] = ea_in[(size_t)e * 19 + k];
    float ea[12];
#pragma unroll
    for (int t = 0; t < 12; ++t) {
      float a = bea[t];
#pragma unroll
      for (int k = 0; k < 19; ++k) a += att[k] * Wea[k * 12 + t];
      ea[t] = fmaxf(a, 0.0f);
    }
#pragma unroll
    for (int ch = 0; ch < 16; ++ch) {
      float acc[8];
#pragma unroll
      for (int i = 0; i < 8; ++i) acc[i] = be1[ch * 8 + i];
#pragma unroll
      for (int j = 0; j < 12; ++j)
#pragma unroll
        for (int i = 0; i < 8; ++i) acc[i] += ea[j] * We1[j * 128 + ch * 8 + i];
      short8v ov;
#pragma unroll
      for (int i = 0; i < 8; ++i) ov[i] = (short)f2bf(fmaxf(acc[i], 0.0f));
      *(short8v*)(Ahi + (size_t)e * 128 + ch * 8) = ov;
    }
  }
}

// Fused conv, r25: f-split + 3 blocks/CU.
//  - grid (E/128, 2): blockIdx.y picks 32 of 64 f; d stays 0..63 per block
//  - per block-iter LDS flow halved: panel 8KB, B-read 16KB, stage 8KB
//  - hsT [64][128] f32 XOR-swizzled (col = r ^ ((s&7)<<2)): pad removed,
//    write conflicts 16->2-way, reads conflict-free & 16B-aligned
//  - LDS 53248 B -> 3 blk/CU (156KB), 3 waves/SIMD for phase decorrelation
__global__ __launch_bounds__(256, 3) void k_conv_fused(
    const u16* __restrict__ Ahi, const u16* __restrict__ Bph,
    const float* __restrict__ b2, const float* __restrict__ h,
    const int* __restrict__ src, const int* __restrict__ pos,
    u16* __restrict__ msgh, int E) {
  __shared__ __align__(16) u16 sB[2][4096];     // 2 x 8 KB B half-panels
  __shared__ __align__(16) float hsT[64 * 128]; // h[src[e], d] transposed+swizzled
  __shared__ __align__(16) u16 sb2h[2048];      // b2[d][fbase..fbase+32) as bf16
  int m0 = blockIdx.x * 128;
  int y = blockIdx.y;             // f-half: fbase = y*32
  int tid = threadIdx.x;
  int wave = tid >> 6, lane = tid & 63;
  int mw = wave >> 1, fw = wave & 1;  // m-group (64 edges), f-sub (16 f)
  int c = lane & 15, q = lane >> 4;

  // stage the 8KB f-half of panel d: wave w = ks-chunk w, columns nt in {2y,2y+1}
  auto stageB = [&](int d, int b) {
    const u16* gp = Bph + (size_t)d * 8192 + wave * 2048 + y * 1024 + lane * 8;
    u16* lp = &sB[b][wave * 1024];
#pragma unroll
    for (int i = 0; i < 2; ++i)
      __builtin_amdgcn_global_load_lds(
          (const __attribute__((address_space(1))) unsigned int*)(gp + i * 512),
          (__attribute__((address_space(3))) unsigned int*)(lp + i * 512), 16, 0, 0);
  };

  stageB(0, 0);  // first panel in flight under the prologue

  // A fragments: 4 m-tiles x 4 k-slices, global->reg, held for whole kernel
  short8v afr[4][4];
#pragma unroll
  for (int mt = 0; mt < 4; ++mt) {
    int gr = m0 + mw * 64 + mt * 16 + c;
    if (gr >= E) gr = E - 1;
    const u16* ap = Ahi + (size_t)gr * 128 + q * 8;
#pragma unroll
    for (int ks = 0; ks < 4; ++ks) afr[mt][ks] = *(const short8v*)(ap + ks * 32);
  }

  // hsT: transposed+swizzled stage of h[src[e], 0:64]
#pragma unroll
  for (int p = 0; p < 8; ++p) {
    int slot = p * 256 + tid;
    int r = slot >> 4, s = slot & 15;  // edge r, d-quad s
    int ge = m0 + r;
    if (ge >= E) ge = E - 1;
    int sn = src[ge];
    float4 v = *(const float4*)(h + (size_t)sn * 64 + s * 4);
    int col = r ^ ((s & 7) << 2);
    hsT[(s * 4 + 0) * 128 + col] = v.x;
    hsT[(s * 4 + 1) * 128 + col] = v.y;
    hsT[(s * 4 + 2) * 128 + col] = v.z;
    hsT[(s * 4 + 3) * 128 + col] = v.w;
  }
  // sb2h: b2[d][fbase..fbase+32) as bf16 (2048 entries)
  {
#pragma unroll
    for (int i = 0; i < 8; ++i) {
      int idx = tid * 8 + i;
      int dl = idx >> 5, fl = idx & 31;
      sb2h[idx] = f2bf(b2[(size_t)dl * 64 + y * 32 + fl]);
    }
  }
  __syncthreads();  // panel0 + hsT + sb2h ready

  float msg[4][4];
#pragma unroll
  for (int mt = 0; mt < 4; ++mt)
#pragma unroll
    for (int r = 0; r < 4; ++r) msg[mt][r] = 0.0f;

  int cur = 0;
  for (int dl = 0; dl < 64; ++dl) {
    if (dl < 63) stageB(dl + 1, cur ^ 1);
    float b2v = bf2f(sb2h[dl * 32 + fw * 16 + c]);
    float4v acc[4];
#pragma unroll
    for (int mt = 0; mt < 4; ++mt) acc[mt] = (float4v){0.f, 0.f, 0.f, 0.f};
    __builtin_amdgcn_s_setprio(1);
#pragma unroll
    for (int ks = 0; ks < 4; ++ks) {
      short8v bfrag = *(const short8v*)(&sB[cur][ks * 1024 + fw * 512 + lane * 8]);
#pragma unroll
      for (int mt = 0; mt < 4; ++mt)
        acc[mt] = __builtin_amdgcn_mfma_f32_16x16x32_bf16(afr[mt][ks], bfrag, acc[mt], 0, 0, 0);
    }
    __builtin_amdgcn_s_setprio(0);
    int swz = ((dl >> 2) & 7) << 2;
#pragma unroll
    for (int mt = 0; mt < 4; ++mt) {
      float4 hd4 = *(const float4*)(&hsT[dl * 128 + ((mw * 64 + mt * 16 + q * 4) ^ swz)]);
      float hd[4] = {hd4.x, hd4.y, hd4.z, hd4.w};
#pragma unroll
      for (int r = 0; r < 4; ++r) msg[mt][r] += hd[r] * (acc[mt][r] + b2v);
    }
    __syncthreads();
    cur ^= 1;
  }

  // bf16 stores pre-permuted to CSR slot order; y-half owns cols [y*32, y*32+32)
#pragma unroll
  for (int mt = 0; mt < 4; ++mt) {
#pragma unroll
    for (int r = 0; r < 4; ++r) {
      int e = m0 + mw * 64 + mt * 16 + q * 4 + r;
      if (e < E) {
        int pe = pos[e];
        msgh[(size_t)pe * 64 + y * 32 + fw * 16 + c] = f2bf(msg[mt][r]);
      }
    }
  }
}

// MFMA GRU, r24: bf16 msgh gather   [verified r24]
__global__ __launch_bounds__(256, 2) void k_gru_mfma(
    const u16* __restrict__ msgh, const int* __restrict__ row,
    const float* __restrict__ cb, const u16* __restrict__ WpI,
    const u16* __restrict__ WpH, const float* __restrict__ bih,
    const float* __restrict__ bhh, const float* __restrict__ hin,
    float* __restrict__ hout, int N) {
  __shared__ __align__(16) u16 sM[64 * 72];
  __shared__ __align__(16) u16 sH[64 * 72];
  __shared__ __align__(16) float sHf[64 * 68];
  __shared__ int sRow[65];
  int n0 = blockIdx.x * 64;
  int tid = threadIdx.x;
  if (tid < 65) {
    int idx = n0 + tid;
    sRow[tid] = row[(idx <= N) ? idx : N];
  }
  __syncthreads();
  {
    int nl = tid >> 4, fq = tid & 15;
    float4 cbv = *(const float4*)(cb + fq * 4);
#pragma unroll
    for (int pass = 0; pass < 4; ++pass) {
      int n = pass * 16 + nl;
      int gn = n0 + n;
      bool real = (gn < N);
      int b0 = sRow[n], b1 = sRow[n + 1];
      if (!real) b1 = b0;
      float4 av = {0.f, 0.f, 0.f, 0.f};
      for (int j = b0; j < b1; ++j) {
        ushort4 mv = *(const ushort4*)(msgh + (size_t)j * 64 + fq * 4);
        av.x += bf2f(mv.x); av.y += bf2f(mv.y);
        av.z += bf2f(mv.z); av.w += bf2f(mv.w);
      }
      float cf = fmaxf((float)(b1 - b0), 1.0f);
      int hgn = real ? gn : N - 1;
      float4 hv = *(const float4*)(hin + (size_t)hgn * 64 + fq * 4);
      float m0v = fmaxf(av.x / cf + cbv.x, 0.0f);
      float m1v = fmaxf(av.y / cf + cbv.y, 0.0f);
      float m2v = fmaxf(av.z / cf + cbv.z, 0.0f);
      float m3v = fmaxf(av.w / cf + cbv.w, 0.0f);
      ushort4 mu; mu.x = f2bf(m0v); mu.y = f2bf(m1v); mu.z = f2bf(m2v); mu.w = f2bf(m3v);
      ushort4 hu; hu.x = f2bf(hv.x); hu.y = f2bf(hv.y); hu.z = f2bf(hv.z); hu.w = f2bf(hv.w);
      *(ushort4*)(&sM[n * 72 + fq * 4]) = mu;
      *(ushort4*)(&sH[n * 72 + fq * 4]) = hu;
      *(float4*)(&sHf[n * 68 + fq * 4]) = hv;
    }
  }
  __syncthreads();
  int wave = tid >> 6, lane = tid & 63;
  int c = lane & 15, q = lane >> 4;
  short8v am[2], ah[2];
#pragma unroll
  for (int ks = 0; ks < 2; ++ks) {
    am[ks] = *(const short8v*)(&sM[(wave * 16 + c) * 72 + ks * 32 + q * 8]);
    ah[ks] = *(const short8v*)(&sH[(wave * 16 + c) * 72 + ks * 32 + q * 8]);
  }
  float4v accRZ[8], accN[4], accHN[4];
#pragma unroll
  for (int i = 0; i < 8; ++i) accRZ[i] = (float4v){0.f, 0.f, 0.f, 0.f};
#pragma unroll
  for (int i = 0; i < 4; ++i) {
    accN[i] = (float4v){0.f, 0.f, 0.f, 0.f};
    accHN[i] = (float4v){0.f, 0.f, 0.f, 0.f};
  }
#pragma unroll
  for (int ks = 0; ks < 2; ++ks) {
#pragma unroll
    for (int nt = 0; nt < 8; ++nt) {
      short8v bI = *(const short8v*)(WpI + ((size_t)(ks * 12 + nt) * 64 + lane) * 8);
      short8v bH = *(const short8v*)(WpH + ((size_t)(ks * 12 + nt) * 64 + lane) * 8);
      accRZ[nt] = __builtin_amdgcn_mfma_f32_16x16x32_bf16(am[ks], bI, accRZ[nt], 0, 0, 0);
      accRZ[nt] = __builtin_amdgcn_mfma_f32_16x16x32_bf16(ah[ks], bH, accRZ[nt], 0, 0, 0);
    }
#pragma unroll
    for (int nt = 0; nt < 4; ++nt) {
      short8v bI = *(const short8v*)(WpI + ((size_t)(ks * 12 + 8 + nt) * 64 + lane) * 8);
      short8v bH = *(const short8v*)(WpH + ((size_t)(ks * 12 + 8 + nt) * 64 + lane) * 8);
      accN[nt] = __builtin_amdgcn_mfma_f32_16x16x32_bf16(am[ks], bI, accN[nt], 0, 0, 0);
      accHN[nt] = __builtin_amdgcn_mfma_f32_16x16x32_bf16(ah[ks], bH, accHN[nt], 0, 0, 0);
    }
  }
#pragma unroll
  for (int nt = 0; nt < 4; ++nt) {
    int f = nt * 16 + c;
    float brz_r = bih[f] + bhh[f];
    float brz_z = bih[64 + f] + bhh[64 + f];
    float bin = bih[128 + f];
    float bhn = bhh[128 + f];
#pragma unroll
    for (int r = 0; r < 4; ++r) {
      int nl = wave * 16 + q * 4 + r;
      int gn = n0 + nl;
      float rr = sigm(accRZ[nt][r] + brz_r);
      float zz = sigm(accRZ[nt + 4][r] + brz_z);
      float ng = tanhf(accN[nt][r] + bin + rr * (accHN[nt][r] + bhn));
      float hv = sHf[nl * 68 + f];
      if (gn < N) hout[(size_t)gn * 64 + f] = (1.0f - zz) * ng + zz * hv;
    }
  }
}

// MFMA final MLP, r23-vectorized staging   [verified r23]
__global__ __launch_bounds__(256) void k_final_mfma(
    const float* __restrict__ h, const float* __restrict__ ea3,
    const int* __restrict__ idx3, const u16* __restrict__ Wp1,
    const float* __restrict__ bl1, const float* __restrict__ Wl2,
    const float* __restrict__ bl2, float* __restrict__ out, int E3) {
  __shared__ __align__(16) u16 sF[64 * 104];
  int e0 = blockIdx.x * 64;
  int tid = threadIdx.x;
  {
    int er = tid >> 2;
    int part = tid & 3;
    int ge = e0 + er;
    int gc = (ge < E3) ? ge : E3 - 1;
    int a = idx3[gc], b = idx3[E3 + gc];
    const float* pa = h + (size_t)a * 64 + part * 16;
    const float* pb = h + (size_t)b * 64 + part * 16;
#pragma unroll
    for (int u = 0; u < 4; ++u) {
      float4 va = *(const float4*)(pa + u * 4);
      float4 vb = *(const float4*)(pb + u * 4);
      ushort4 mu;
      mu.x = f2bf(0.5f * (va.x + vb.x));
      mu.y = f2bf(0.5f * (va.y + vb.y));
      mu.z = f2bf(0.5f * (va.z + vb.z));
      mu.w = f2bf(0.5f * (va.w + vb.w));
      *(ushort4*)(&sF[er * 104 + part * 16 + u * 4]) = mu;
    }
    if (part == 0) {
      float4 e0v = *(const float4*)(ea3 + (size_t)gc * 8);
      float4 e1v = *(const float4*)(ea3 + (size_t)gc * 8 + 4);
      ushort4 u0, u1;
      u0.x = f2bf(e0v.x); u0.y = f2bf(e0v.y); u0.z = f2bf(e0v.z); u0.w = f2bf(e0v.w);
      u1.x = f2bf(e1v.x); u1.y = f2bf(e1v.y); u1.z = f2bf(e1v.z); u1.w = f2bf(e1v.w);
      *(ushort4*)(&sF[er * 104 + 64]) = u0;
      *(ushort4*)(&sF[er * 104 + 68]) = u1;
    } else {
      ushort4 z = {0, 0, 0, 0};
      *(ushort4*)(&sF[er * 104 + 72 + (part - 1) * 8]) = z;
      *(ushort4*)(&sF[er * 104 + 76 + (part - 1) * 8]) = z;
    }
  }
  __syncthreads();
  int wave = tid >> 6, lane = tid & 63;
  int c = lane & 15, q = lane >> 4;
  float4v acc[8];
#pragma unroll
  for (int nt = 0; nt < 8; ++nt) acc[nt] = (float4v){0.f, 0.f, 0.f, 0.f};
#pragma unroll
  for (int ks = 0; ks < 3; ++ks) {
    short8v af = *(const short8v*)(&sF[(wave * 16 + c) * 104 + ks * 32 + q * 8]);
#pragma unroll
    for (int nt = 0; nt < 8; ++nt) {
      short8v bf = *(const short8v*)(Wp1 + ((size_t)(ks * 8 + nt) * 64 + lane) * 8);
      acc[nt] = __builtin_amdgcn_mfma_f32_16x16x32_bf16(af, bf, acc[nt], 0, 0, 0);
    }
  }
  float v[4] = {0.f, 0.f, 0.f, 0.f};
#pragma unroll
  for (int nt = 0; nt < 8; ++nt) {
    int n = nt * 16 + c;
    float b1 = bl1[n];
    float w2 = Wl2[n];
#pragma unroll
    for (int r = 0; r < 4; ++r) v[r] += fmaxf(acc[nt][r] + b1, 0.0f) * w2;
  }
#pragma unroll
  for (int off = 1; off < 16; off <<= 1) {
#pragma unroll
    for (int r = 0; r < 4; ++r) v[r] += __shfl_xor(v[r], off);
  }
  if (c == 0) {
    float b2v = bl2[0];
#pragma unroll
    for (int r = 0; r < 4; ++r) {
      int e = e0 + wave * 16 + q * 4 + r;
      if (e < E3) out[e] = v[r] + b2v;
    }
  }
}

extern "C" void kernel_launch(void* const* d_in, const int* in_sizes, int n_in,
                              void* d_out, int out_size, void* d_ws, size_t ws_size,
                              hipStream_t stream) {
  const float* x          = (const float*)d_in[0];
  const float* edge_attr  = (const float*)d_in[1];
  const float* edge_attr3 = (const float*)d_in[2];
  const int*   edge_index = (const int*)d_in[3];
  const int*   edge_index3= (const int*)d_in[4];
  const float* W_node = (const float*)d_in[5];
  const float* b_node = (const float*)d_in[6];
  const float* W_ea   = (const float*)d_in[7];
  const float* b_ea   = (const float*)d_in[8];
  const float* W_e1   = (const float*)d_in[9];
  const float* b_e1   = (const float*)d_in[10];
  const float* W_e2   = (const float*)d_in[11];
  const float* b_e2   = (const float*)d_in[12];
  const float* conv_bias = (const float*)d_in[13];
  const float* W_ih   = (const float*)d_in[14];
  const float* b_ih   = (const float*)d_in[15];
  const float* W_hh   = (const float*)d_in[16];
  const float* b_hh   = (const float*)d_in[17];
  const float* W_l1   = (const float*)d_in[18];
  const float* b_l1   = (const float*)d_in[19];
  const float* W_l2   = (const float*)d_in[20];
  const float* b_l2   = (const float*)d_in[21];

  int N  = in_sizes[0] / 8;
  int E  = in_sizes[1] / 19;
  int E3 = in_sizes[2] / 8;

  char* p = (char*)d_ws;
  auto carve = [&](size_t bytes) -> void* {
    char* q = p;
    p += (bytes + 255) & ~(size_t)255;
    return (void*)q;
  };
  float* hA    = (float*)carve((size_t)N * 64 * 4);
  float* hB    = (float*)carve((size_t)N * 64 * 4);
  u16*   msgh  = (u16*)carve((size_t)E * 64 * 2);
  int*   cnt   = (int*)carve((size_t)N * 4);
  int*   row   = (int*)carve((size_t)(N + 1) * 4);
  int*   cursor= (int*)carve((size_t)N * 4);
  int*   pos   = (int*)carve((size_t)E * 4);
  int*   bsum  = (int*)carve(256 * 4);
  u16*   Ahi   = (u16*)carve((size_t)E * 128 * 2);
  u16*   Bph   = (u16*)carve((size_t)128 * 4096 * 2);
  u16*   WpI   = (u16*)carve(12288 * 2);
  u16*   WpH   = (u16*)carve(12288 * 2);
  u16*   Wp1   = (u16*)carve(12288 * 2);

  const int* src = edge_index;
  const int* dst = edge_index + E;

  int nb = (N + 255) / 256;
  // CSR build (once)
  hipMemsetAsync(cnt, 0, (size_t)N * 4, stream);
  k_cnt<<<(E + 255) / 256, 256, 0, stream>>>(dst, cnt, E);
  k_scan1<<<nb, 256, 0, stream>>>(cnt, bsum, N);
  k_scan2<<<1, 256, 0, stream>>>(bsum, row, nb, N);
  k_scan3<<<nb, 256, 0, stream>>>(cnt, bsum, row, cursor, N);
  k_pos<<<(E + 255) / 256, 256, 0, stream>>>(dst, cursor, pos, E);

  int nbNode = ((size_t)N * 64 + 255) / 256;
  int nbPack = (128 * 4096 + 255) / 256;
  int nbWtf  = (2 * 12288 + 255) / 256;
  int nbWl1  = (12288 + 255) / 256;
  int nbEdge = (E + 255) / 256;
  k_prep_all<<<nbNode + nbPack + nbWtf + nbWl1 + nbEdge, 256, 0, stream>>>(
      x, W_node, b_node, hA, N, nbNode, W_e2, Bph, nbPack,
      W_ih, W_hh, WpI, WpH, nbWtf, W_l1, Wp1, nbWl1,
      edge_attr, W_ea, b_ea, W_e1, b_e1, Ahi, E);

  float* hcur = hA;
  float* hnxt = hB;
  dim3 gconv((E + 127) / 128, 2);
  int ngru = (N + 63) / 64;
  for (int it = 0; it < 3; ++it) {
    k_conv_fused<<<gconv, 256, 0, stream>>>(Ahi, Bph, b_e2, hcur, src, pos, msgh, E);
    k_gru_mfma<<<ngru, 256, 0, stream>>>(msgh, row, conv_bias, WpI, WpH,
                                         b_ih, b_hh, hcur, hnxt, N);
    float* tmp = hcur; hcur = hnxt; hnxt = tmp;
  }
  k_final_mfma<<<(E3 + 63) / 64, 256, 0, stream>>>(hcur, edge_attr3, edge_index3, Wp1,
                                                   b_l1, W_l2, b_l2, (float*)d_out, E3);
}

// Round 8
// 429.341 us; speedup vs baseline: 1.1835x; 1.1835x over previous
//
#include <hip/hip_runtime.h>

typedef unsigned short u16;
typedef unsigned int u32;
typedef __attribute__((ext_vector_type(8))) short short8v;
typedef __attribute__((ext_vector_type(4))) float float4v;

__device__ __forceinline__ float sigm(float x) { return 1.0f / (1.0f + __expf(-x)); }
__device__ __forceinline__ u16 f2bf(float f) {
  u32 u = __float_as_uint(f);
  u32 r = (u + 0x7fffu + ((u >> 16) & 1u)) >> 16;
  return (u16)r;
}
__device__ __forceinline__ float bf2f(u16 w) { return __uint_as_float(((u32)w) << 16); }

__global__ void k_cnt(const int* __restrict__ dst, int* __restrict__ cnt, int E) {
  int e = blockIdx.x * blockDim.x + threadIdx.x;
  if (e < E) atomicAdd(&cnt[dst[e]], 1);
}

// --- parallel scan: scan1 block sums -> scan2 scan of ~98 sums -> scan3 local scan ---
__global__ void k_scan1(const int* __restrict__ cnt, int* __restrict__ bsum, int N) {
  __shared__ int ws[4];
  int t = threadIdx.x;
  int i = blockIdx.x * 256 + t;
  int v = (i < N) ? cnt[i] : 0;
  int s = v;
  for (int off = 1; off < 64; off <<= 1) s += __shfl_xor(s, off);
  int wid = t >> 6, lane = t & 63;
  if (lane == 0) ws[wid] = s;
  __syncthreads();
  if (t == 0) bsum[blockIdx.x] = ws[0] + ws[1] + ws[2] + ws[3];
}

__global__ void k_scan2(int* __restrict__ bsum, int* __restrict__ row, int nb, int N) {
  __shared__ int s[256];
  int t = threadIdx.x;
  if (t < nb) s[t] = bsum[t];
  __syncthreads();
  if (t == 0) {
    int run = 0;
    for (int i = 0; i < nb; ++i) { int x = s[i]; s[i] = run; run += x; }
    row[N] = run;
  }
  __syncthreads();
  if (t < nb) bsum[t] = s[t];
}

__global__ void k_scan3(const int* __restrict__ cnt, const int* __restrict__ bsum,
                        int* __restrict__ row, int* __restrict__ cursor, int N) {
  __shared__ int ws[4];
  int t = threadIdx.x;
  int i = blockIdx.x * 256 + t;
  int v = (i < N) ? cnt[i] : 0;
  int lane = t & 63, wid = t >> 6;
  int incl = v;
  for (int off = 1; off < 64; off <<= 1) {
    int u = __shfl_up(incl, off);
    if (lane >= off) incl += u;
  }
  if (lane == 63) ws[wid] = incl;
  __syncthreads();
  int woff = bsum[blockIdx.x];
  for (int w = 0; w < wid; ++w) woff += ws[w];
  int excl = woff + incl - v;
  if (i < N) { row[i] = excl; cursor[i] = excl; }
}

// pos[e] = CSR slot of edge e (counting sort position among same-dst edges)
__global__ void k_pos(const int* __restrict__ dst, int* __restrict__ cursor,
                      int* __restrict__ pos, int E) {
  int e = blockIdx.x * blockDim.x + threadIdx.x;
  if (e < E) pos[e] = atomicAdd(&cursor[dst[e]], 1);
}

// Fused prep, r26: node MLP + W_e2 pack + GRU packs + W_l1 pack + flat edge MLP
// (edge MLP 1-thread-per-edge, 196 blocks -- replaces the 25000-block dispatch;
//  logic validated in r25)
__global__ void k_prep_all(
    const float* __restrict__ x, const float* __restrict__ Wn,
    const float* __restrict__ bn, float* __restrict__ h, int N, int nbNode,
    const float* __restrict__ W2, u16* __restrict__ Bph, int nbPack,
    const float* __restrict__ Wih, const float* __restrict__ Whh,
    u16* __restrict__ WpI, u16* __restrict__ WpH, int nbWtf,
    const float* __restrict__ Wl1, u16* __restrict__ Wp1, int nbWl1,
    const float* __restrict__ ea_in, const float* __restrict__ Wea,
    const float* __restrict__ bea, const float* __restrict__ We1,
    const float* __restrict__ be1, u16* __restrict__ Ahi, int E) {
  int b = blockIdx.x;
  if (b < nbNode) {
    int tid = b * 256 + threadIdx.x;
    if (tid >= N * 64) return;
    int n = tid >> 6, f = tid & 63;
    float acc = bn[f];
    for (int k = 0; k < 8; ++k) acc += x[(size_t)n * 8 + k] * Wn[k * 64 + f];
    h[tid] = fmaxf(acc, 0.0f);
  } else if (b < nbNode + nbPack) {
    int tid = (b - nbNode) * 256 + threadIdx.x;
    if (tid >= 128 * 4096) return;
    int j = tid & 7;
    int lane = (tid >> 3) & 63;
    int nt = (tid >> 9) & 3;
    int ks = (tid >> 11) & 3;
    int d = tid >> 13;
    int c = lane & 15, q = lane >> 4;
    int k = ks * 32 + q * 8 + j;
    int n = d * 64 + nt * 16 + c;
    Bph[tid] = f2bf(W2[(size_t)k * 4096 + n]);
  } else if (b < nbNode + nbPack + nbWtf) {
    int tid = (b - nbNode - nbPack) * 256 + threadIdx.x;
    if (tid >= 2 * 12288) return;
    int w = tid / 12288;
    int r = tid - w * 12288;
    int jj = r & 7;
    int lane = (r >> 3) & 63;
    int t = r >> 9;
    int nt = t % 12, ks = t / 12;
    int c = lane & 15, q = lane >> 4;
    int j = nt * 16 + c;
    int k = ks * 32 + q * 8 + jj;
    const float* W = w ? Whh : Wih;
    u16* Wp = w ? WpH : WpI;
    Wp[r] = f2bf(W[j * 64 + k]);
  } else if (b < nbNode + nbPack + nbWtf + nbWl1) {
    int tid = (b - nbNode - nbPack - nbWtf) * 256 + threadIdx.x;
    if (tid >= 3 * 8 * 64 * 8) return;
    int j = tid & 7;
    int lane = (tid >> 3) & 63;
    int nt = (tid >> 9) & 7;
    int ks = tid >> 12;
    int c = lane & 15, q = lane >> 4;
    int k = ks * 32 + q * 8 + j;
    int n = nt * 16 + c;
    Wp1[tid] = f2bf((k < 72) ? Wl1[k * 128 + n] : 0.0f);
  } else {
    // flat edge MLP: one thread per edge
    int e = (b - nbNode - nbPack - nbWtf - nbWl1) * 256 + threadIdx.x;
    if (e >= E) return;
    float att[19];
#pragma unroll
    for (int k = 0; k < 19; ++k) att[k] = ea_in[(size_t)e * 19 + k];
    float ea[12];
#pragma unroll
    for (int t = 0; t < 12; ++t) {
      float a = bea[t];
#pragma unroll
      for (int k = 0; k < 19; ++k) a += att[k] * Wea[k * 12 + t];
      ea[t] = fmaxf(a, 0.0f);
    }
#pragma unroll
    for (int ch = 0; ch < 16; ++ch) {
      float acc[8];
#pragma unroll
      for (int i = 0; i < 8; ++i) acc[i] = be1[ch * 8 + i];
#pragma unroll
      for (int j = 0; j < 12; ++j)
#pragma unroll
        for (int i = 0; i < 8; ++i) acc[i] += ea[j] * We1[j * 128 + ch * 8 + i];
      short8v ov;
#pragma unroll
      for (int i = 0; i < 8; ++i) ov[i] = (short)f2bf(fmaxf(acc[i], 0.0f));
      *(short8v*)(Ahi + (size_t)e * 128 + ch * 8) = ov;
    }
  }
}

// Fused conv, r26 = r24 structure (verified 74.2us) + hsT XOR-swizzle
// (swizzle verified in r25: write col = r ^ ((s&7)<<2), read ^ swz(dl);
//  per-block bank conflicts ~8x down, 4KB LDS saved).
// LDS = 32768(Bdbuf) + 32768(hsT 64x128) + 8192(sb2h) = 73728 B -> 2 blk/CU.
__global__ __launch_bounds__(256, 2) void k_conv_fused(
    const u16* __restrict__ Ahi, const u16* __restrict__ Bph,
    const float* __restrict__ b2, const float* __restrict__ h,
    const int* __restrict__ src, const int* __restrict__ pos,
    u16* __restrict__ msgh, int E) {
  __shared__ __align__(16) u16 sB[2][8192];     // 2 x 16 KB B panels
  __shared__ __align__(16) float hsT[64 * 128]; // h[src[e], d] transposed+swizzled
  __shared__ __align__(16) u16 sb2h[4096];      // b2 as bf16
  int m0 = blockIdx.x * 128;
  int tid = threadIdx.x;
  int wave = tid >> 6, lane = tid & 63;
  int mw = wave >> 1, fw = wave & 1;
  int c = lane & 15, q = lane >> 4;

  auto stageB = [&](int d, int b) {
    const u16* gp = Bph + (size_t)d * 8192 + wave * 2048 + lane * 8;
    u16* lp = &sB[b][wave * 2048];
#pragma unroll
    for (int i = 0; i < 4; ++i)
      __builtin_amdgcn_global_load_lds(
          (const __attribute__((address_space(1))) unsigned int*)(gp + i * 512),
          (__attribute__((address_space(3))) unsigned int*)(lp + i * 512), 16, 0, 0);
  };

  stageB(0, 0);  // first panel in flight under the prologue

  // A fragments: 4 m-tiles x 4 k-slices, global->reg, held for whole kernel
  short8v afr[4][4];
#pragma unroll
  for (int mt = 0; mt < 4; ++mt) {
    int gr = m0 + mw * 64 + mt * 16 + c;
    if (gr >= E) gr = E - 1;
    const u16* ap = Ahi + (size_t)gr * 128 + q * 8;
#pragma unroll
    for (int ks = 0; ks < 4; ++ks) afr[mt][ks] = *(const short8v*)(ap + ks * 32);
  }

  // hsT: transposed+swizzled stage of h[src[e], 0:64]
#pragma unroll
  for (int p = 0; p < 8; ++p) {
    int slot = p * 256 + tid;
    int r = slot >> 4, s = slot & 15;  // edge r, d-quad s
    int ge = m0 + r;
    if (ge >= E) ge = E - 1;
    int sn = src[ge];
    float4 v = *(const float4*)(h + (size_t)sn * 64 + s * 4);
    int col = r ^ ((s & 7) << 2);
    hsT[(s * 4 + 0) * 128 + col] = v.x;
    hsT[(s * 4 + 1) * 128 + col] = v.y;
    hsT[(s * 4 + 2) * 128 + col] = v.z;
    hsT[(s * 4 + 3) * 128 + col] = v.w;
  }
  // sb2h: all 4096 b2 values as bf16
  {
    int t16 = tid * 16;
#pragma unroll
    for (int u = 0; u < 4; ++u) {
      float4 v = *(const float4*)(b2 + t16 + u * 4);
      sb2h[t16 + u * 4 + 0] = f2bf(v.x);
      sb2h[t16 + u * 4 + 1] = f2bf(v.y);
      sb2h[t16 + u * 4 + 2] = f2bf(v.z);
      sb2h[t16 + u * 4 + 3] = f2bf(v.w);
    }
  }
  __syncthreads();  // panel0 + hsT + sb2h ready

  float msg[4][2][4];
#pragma unroll
  for (int mt = 0; mt < 4; ++mt)
#pragma unroll
    for (int nt = 0; nt < 2; ++nt)
#pragma unroll
      for (int r = 0; r < 4; ++r) msg[mt][nt][r] = 0.0f;

  int cur = 0;
  for (int dl = 0; dl < 64; ++dl) {
    if (dl < 63) stageB(dl + 1, cur ^ 1);
    float b2v0 = bf2f(sb2h[dl * 64 + fw * 32 + c]);
    float b2v1 = bf2f(sb2h[dl * 64 + fw * 32 + 16 + c]);
    float4v acc[4][2];
#pragma unroll
    for (int mt = 0; mt < 4; ++mt)
#pragma unroll
      for (int nt = 0; nt < 2; ++nt) acc[mt][nt] = (float4v){0.f, 0.f, 0.f, 0.f};
    __builtin_amdgcn_s_setprio(1);
#pragma unroll
    for (int ks = 0; ks < 4; ++ks) {
      short8v b0 = *(const short8v*)(&sB[cur][ks * 2048 + fw * 1024 + lane * 8]);
      short8v b1 = *(const short8v*)(&sB[cur][ks * 2048 + fw * 1024 + 512 + lane * 8]);
#pragma unroll
      for (int mt = 0; mt < 4; ++mt) {
        acc[mt][0] = __builtin_amdgcn_mfma_f32_16x16x32_bf16(afr[mt][ks], b0, acc[mt][0], 0, 0, 0);
        acc[mt][1] = __builtin_amdgcn_mfma_f32_16x16x32_bf16(afr[mt][ks], b1, acc[mt][1], 0, 0, 0);
      }
    }
    __builtin_amdgcn_s_setprio(0);
    int swz = ((dl >> 2) & 7) << 2;
#pragma unroll
    for (int mt = 0; mt < 4; ++mt) {
      float4 hd4 = *(const float4*)(&hsT[dl * 128 + ((mw * 64 + mt * 16 + q * 4) ^ swz)]);
      float hd[4] = {hd4.x, hd4.y, hd4.z, hd4.w};
#pragma unroll
      for (int r = 0; r < 4; ++r) {
        msg[mt][0][r] += hd[r] * (acc[mt][0][r] + b2v0);
        msg[mt][1][r] += hd[r] * (acc[mt][1][r] + b2v1);
      }
    }
    __syncthreads();
    cur ^= 1;
  }

  // bf16 stores pre-permuted to CSR slot order: GRU reads contiguous rows
#pragma unroll
  for (int mt = 0; mt < 4; ++mt) {
#pragma unroll
    for (int r = 0; r < 4; ++r) {
      int e = m0 + mw * 64 + mt * 16 + q * 4 + r;
      if (e < E) {
        int pe = pos[e];
        u16* mp = msgh + (size_t)pe * 64 + fw * 32 + c;
        mp[0] = f2bf(msg[mt][0][r]);
        mp[16] = f2bf(msg[mt][1][r]);
      }
    }
  }
}

// MFMA GRU, r24: bf16 msgh gather   [verified r24]
__global__ __launch_bounds__(256, 2) void k_gru_mfma(
    const u16* __restrict__ msgh, const int* __restrict__ row,
    const float* __restrict__ cb, const u16* __restrict__ WpI,
    const u16* __restrict__ WpH, const float* __restrict__ bih,
    const float* __restrict__ bhh, const float* __restrict__ hin,
    float* __restrict__ hout, int N) {
  __shared__ __align__(16) u16 sM[64 * 72];
  __shared__ __align__(16) u16 sH[64 * 72];
  __shared__ __align__(16) float sHf[64 * 68];
  __shared__ int sRow[65];
  int n0 = blockIdx.x * 64;
  int tid = threadIdx.x;
  if (tid < 65) {
    int idx = n0 + tid;
    sRow[tid] = row[(idx <= N) ? idx : N];
  }
  __syncthreads();
  {
    int nl = tid >> 4, fq = tid & 15;
    float4 cbv = *(const float4*)(cb + fq * 4);
#pragma unroll
    for (int pass = 0; pass < 4; ++pass) {
      int n = pass * 16 + nl;
      int gn = n0 + n;
      bool real = (gn < N);
      int b0 = sRow[n], b1 = sRow[n + 1];
      if (!real) b1 = b0;
      float4 av = {0.f, 0.f, 0.f, 0.f};
      for (int j = b0; j < b1; ++j) {
        ushort4 mv = *(const ushort4*)(msgh + (size_t)j * 64 + fq * 4);
        av.x += bf2f(mv.x); av.y += bf2f(mv.y);
        av.z += bf2f(mv.z); av.w += bf2f(mv.w);
      }
      float cf = fmaxf((float)(b1 - b0), 1.0f);
      int hgn = real ? gn : N - 1;
      float4 hv = *(const float4*)(hin + (size_t)hgn * 64 + fq * 4);
      float m0v = fmaxf(av.x / cf + cbv.x, 0.0f);
      float m1v = fmaxf(av.y / cf + cbv.y, 0.0f);
      float m2v = fmaxf(av.z / cf + cbv.z, 0.0f);
      float m3v = fmaxf(av.w / cf + cbv.w, 0.0f);
      ushort4 mu; mu.x = f2bf(m0v); mu.y = f2bf(m1v); mu.z = f2bf(m2v); mu.w = f2bf(m3v);
      ushort4 hu; hu.x = f2bf(hv.x); hu.y = f2bf(hv.y); hu.z = f2bf(hv.z); hu.w = f2bf(hv.w);
      *(ushort4*)(&sM[n * 72 + fq * 4]) = mu;
      *(ushort4*)(&sH[n * 72 + fq * 4]) = hu;
      *(float4*)(&sHf[n * 68 + fq * 4]) = hv;
    }
  }
  __syncthreads();
  int wave = tid >> 6, lane = tid & 63;
  int c = lane & 15, q = lane >> 4;
  short8v am[2], ah[2];
#pragma unroll
  for (int ks = 0; ks < 2; ++ks) {
    am[ks] = *(const short8v*)(&sM[(wave * 16 + c) * 72 + ks * 32 + q * 8]);
    ah[ks] = *(const short8v*)(&sH[(wave * 16 + c) * 72 + ks * 32 + q * 8]);
  }
  float4v accRZ[8], accN[4], accHN[4];
#pragma unroll
  for (int i = 0; i < 8; ++i) accRZ[i] = (float4v){0.f, 0.f, 0.f, 0.f};
#pragma unroll
  for (int i = 0; i < 4; ++i) {
    accN[i] = (float4v){0.f, 0.f, 0.f, 0.f};
    accHN[i] = (float4v){0.f, 0.f, 0.f, 0.f};
  }
#pragma unroll
  for (int ks = 0; ks < 2; ++ks) {
#pragma unroll
    for (int nt = 0; nt < 8; ++nt) {
      short8v bI = *(const short8v*)(WpI + ((size_t)(ks * 12 + nt) * 64 + lane) * 8);
      short8v bH = *(const short8v*)(WpH + ((size_t)(ks * 12 + nt) * 64 + lane) * 8);
      accRZ[nt] = __builtin_amdgcn_mfma_f32_16x16x32_bf16(am[ks], bI, accRZ[nt], 0, 0, 0);
      accRZ[nt] = __builtin_amdgcn_mfma_f32_16x16x32_bf16(ah[ks], bH, accRZ[nt], 0, 0, 0);
    }
#pragma unroll
    for (int nt = 0; nt < 4; ++nt) {
      short8v bI = *(const short8v*)(WpI + ((size_t)(ks * 12 + 8 + nt) * 64 + lane) * 8);
      short8v bH = *(const short8v*)(WpH + ((size_t)(ks * 12 + 8 + nt) * 64 + lane) * 8);
      accN[nt] = __builtin_amdgcn_mfma_f32_16x16x32_bf16(am[ks], bI, accN[nt], 0, 0, 0);
      accHN[nt] = __builtin_amdgcn_mfma_f32_16x16x32_bf16(ah[ks], bH, accHN[nt], 0, 0, 0);
    }
  }
#pragma unroll
  for (int nt = 0; nt < 4; ++nt) {
    int f = nt * 16 + c;
    float brz_r = bih[f] + bhh[f];
    float brz_z = bih[64 + f] + bhh[64 + f];
    float bin = bih[128 + f];
    float bhn = bhh[128 + f];
#pragma unroll
    for (int r = 0; r < 4; ++r) {
      int nl = wave * 16 + q * 4 + r;
      int gn = n0 + nl;
      float rr = sigm(accRZ[nt][r] + brz_r);
      float zz = sigm(accRZ[nt + 4][r] + brz_z);
      float ng = tanhf(accN[nt][r] + bin + rr * (accHN[nt][r] + bhn));
      float hv = sHf[nl * 68 + f];
      if (gn < N) hout[(size_t)gn * 64 + f] = (1.0f - zz) * ng + zz * hv;
    }
  }
}

// MFMA final MLP, r23-vectorized staging   [verified r23/r24]
__global__ __launch_bounds__(256) void k_final_mfma(
    const float* __restrict__ h, const float* __restrict__ ea3,
    const int* __restrict__ idx3, const u16* __restrict__ Wp1,
    const float* __restrict__ bl1, const float* __restrict__ Wl2,
    const float* __restrict__ bl2, float* __restrict__ out, int E3) {
  __shared__ __align__(16) u16 sF[64 * 104];
  int e0 = blockIdx.x * 64;
  int tid = threadIdx.x;
  {
    int er = tid >> 2;
    int part = tid & 3;
    int ge = e0 + er;
    int gc = (ge < E3) ? ge : E3 - 1;
    int a = idx3[gc], b = idx3[E3 + gc];
    const float* pa = h + (size_t)a * 64 + part * 16;
    const float* pb = h + (size_t)b * 64 + part * 16;
#pragma unroll
    for (int u = 0; u < 4; ++u) {
      float4 va = *(const float4*)(pa + u * 4);
      float4 vb = *(const float4*)(pb + u * 4);
      ushort4 mu;
      mu.x = f2bf(0.5f * (va.x + vb.x));
      mu.y = f2bf(0.5f * (va.y + vb.y));
      mu.z = f2bf(0.5f * (va.z + vb.z));
      mu.w = f2bf(0.5f * (va.w + vb.w));
      *(ushort4*)(&sF[er * 104 + part * 16 + u * 4]) = mu;
    }
    if (part == 0) {
      float4 e0v = *(const float4*)(ea3 + (size_t)gc * 8);
      float4 e1v = *(const float4*)(ea3 + (size_t)gc * 8 + 4);
      ushort4 u0, u1;
      u0.x = f2bf(e0v.x); u0.y = f2bf(e0v.y); u0.z = f2bf(e0v.z); u0.w = f2bf(e0v.w);
      u1.x = f2bf(e1v.x); u1.y = f2bf(e1v.y); u1.z = f2bf(e1v.z); u1.w = f2bf(e1v.w);
      *(ushort4*)(&sF[er * 104 + 64]) = u0;
      *(ushort4*)(&sF[er * 104 + 68]) = u1;
    } else {
      ushort4 z = {0, 0, 0, 0};
      *(ushort4*)(&sF[er * 104 + 72 + (part - 1) * 8]) = z;
      *(ushort4*)(&sF[er * 104 + 76 + (part - 1) * 8]) = z;
    }
  }
  __syncthreads();
  int wave = tid >> 6, lane = tid & 63;
  int c = lane & 15, q = lane >> 4;
  float4v acc[8];
#pragma unroll
  for (int nt = 0; nt < 8; ++nt) acc[nt] = (float4v){0.f, 0.f, 0.f, 0.f};
#pragma unroll
  for (int ks = 0; ks < 3; ++ks) {
    short8v af = *(const short8v*)(&sF[(wave * 16 + c) * 104 + ks * 32 + q * 8]);
#pragma unroll
    for (int nt = 0; nt < 8; ++nt) {
      short8v bf = *(const short8v*)(Wp1 + ((size_t)(ks * 8 + nt) * 64 + lane) * 8);
      acc[nt] = __builtin_amdgcn_mfma_f32_16x16x32_bf16(af, bf, acc[nt], 0, 0, 0);
    }
  }
  float v[4] = {0.f, 0.f, 0.f, 0.f};
#pragma unroll
  for (int nt = 0; nt < 8; ++nt) {
    int n = nt * 16 + c;
    float b1 = bl1[n];
    float w2 = Wl2[n];
#pragma unroll
    for (int r = 0; r < 4; ++r) v[r] += fmaxf(acc[nt][r] + b1, 0.0f) * w2;
  }
#pragma unroll
  for (int off = 1; off < 16; off <<= 1) {
#pragma unroll
    for (int r = 0; r < 4; ++r) v[r] += __shfl_xor(v[r], off);
  }
  if (c == 0) {
    float b2v = bl2[0];
#pragma unroll
    for (int r = 0; r < 4; ++r) {
      int e = e0 + wave * 16 + q * 4 + r;
      if (e < E3) out[e] = v[r] + b2v;
    }
  }
}

extern "C" void kernel_launch(void* const* d_in, const int* in_sizes, int n_in,
                              void* d_out, int out_size, void* d_ws, size_t ws_size,
                              hipStream_t stream) {
  const float* x          = (const float*)d_in[0];
  const float* edge_attr  = (const float*)d_in[1];
  const float* edge_attr3 = (const float*)d_in[2];
  const int*   edge_index = (const int*)d_in[3];
  const int*   edge_index3= (const int*)d_in[4];
  const float* W_node = (const float*)d_in[5];
  const float* b_node = (const float*)d_in[6];
  const float* W_ea   = (const float*)d_in[7];
  const float* b_ea   = (const float*)d_in[8];
  const float* W_e1   = (const float*)d_in[9];
  const float* b_e1   = (const float*)d_in[10];
  const float* W_e2   = (const float*)d_in[11];
  const float* b_e2   = (const float*)d_in[12];
  const float* conv_bias = (const float*)d_in[13];
  const float* W_ih   = (const float*)d_in[14];
  const float* b_ih   = (const float*)d_in[15];
  const float* W_hh   = (const float*)d_in[16];
  const float* b_hh   = (const float*)d_in[17];
  const float* W_l1   = (const float*)d_in[18];
  const float* b_l1   = (const float*)d_in[19];
  const float* W_l2   = (const float*)d_in[20];
  const float* b_l2   = (const float*)d_in[21];

  int N  = in_sizes[0] / 8;
  int E  = in_sizes[1] / 19;
  int E3 = in_sizes[2] / 8;

  char* p = (char*)d_ws;
  auto carve = [&](size_t bytes) -> void* {
    char* q = p;
    p += (bytes + 255) & ~(size_t)255;
    return (void*)q;
  };
  float* hA    = (float*)carve((size_t)N * 64 * 4);
  float* hB    = (float*)carve((size_t)N * 64 * 4);
  u16*   msgh  = (u16*)carve((size_t)E * 64 * 2);
  int*   cnt   = (int*)carve((size_t)N * 4);
  int*   row   = (int*)carve((size_t)(N + 1) * 4);
  int*   cursor= (int*)carve((size_t)N * 4);
  int*   pos   = (int*)carve((size_t)E * 4);
  int*   bsum  = (int*)carve(256 * 4);
  u16*   Ahi   = (u16*)carve((size_t)E * 128 * 2);
  u16*   Bph   = (u16*)carve((size_t)128 * 4096 * 2);
  u16*   WpI   = (u16*)carve(12288 * 2);
  u16*   WpH   = (u16*)carve(12288 * 2);
  u16*   Wp1   = (u16*)carve(12288 * 2);

  const int* src = edge_index;
  const int* dst = edge_index + E;

  int nb = (N + 255) / 256;
  // CSR build (once)
  hipMemsetAsync(cnt, 0, (size_t)N * 4, stream);
  k_cnt<<<(E + 255) / 256, 256, 0, stream>>>(dst, cnt, E);
  k_scan1<<<nb, 256, 0, stream>>>(cnt, bsum, N);
  k_scan2<<<1, 256, 0, stream>>>(bsum, row, nb, N);
  k_scan3<<<nb, 256, 0, stream>>>(cnt, bsum, row, cursor, N);
  k_pos<<<(E + 255) / 256, 256, 0, stream>>>(dst, cursor, pos, E);

  int nbNode = ((size_t)N * 64 + 255) / 256;
  int nbPack = (128 * 4096 + 255) / 256;
  int nbWtf  = (2 * 12288 + 255) / 256;
  int nbWl1  = (12288 + 255) / 256;
  int nbEdge = (E + 255) / 256;
  k_prep_all<<<nbNode + nbPack + nbWtf + nbWl1 + nbEdge, 256, 0, stream>>>(
      x, W_node, b_node, hA, N, nbNode, W_e2, Bph, nbPack,
      W_ih, W_hh, WpI, WpH, nbWtf, W_l1, Wp1, nbWl1,
      edge_attr, W_ea, b_ea, W_e1, b_e1, Ahi, E);

  float* hcur = hA;
  float* hnxt = hB;
  int gconv = (E + 127) / 128;
  int ngru = (N + 63) / 64;
  for (int it = 0; it < 3; ++it) {
    k_conv_fused<<<gconv, 256, 0, stream>>>(Ahi, Bph, b_e2, hcur, src, pos, msgh, E);
    k_gru_mfma<<<ngru, 256, 0, stream>>>(msgh, row, conv_bias, WpI, WpH,
                                         b_ih, b_hh, hcur, hnxt, N);
    float* tmp = hcur; hcur = hnxt; hnxt = tmp;
  }
  k_final_mfma<<<(E3 + 63) / 64, 256, 0, stream>>>(hcur, edge_attr3, edge_index3, Wp1,
                                                   b_l1, W_l2, b_l2, (float*)d_out, E3);
}

// Round 9
// 401.660 us; speedup vs baseline: 1.2651x; 1.0689x over previous
//
#include <hip/hip_runtime.h>

typedef unsigned short u16;
typedef unsigned int u32;
typedef __attribute__((ext_vector_type(8))) short short8v;
typedef __attribute__((ext_vector_type(4))) float float4v;

__device__ __forceinline__ float sigm(float x) { return 1.0f / (1.0f + __expf(-x)); }
__device__ __forceinline__ u16 f2bf(float f) {
  u32 u = __float_as_uint(f);
  u32 r = (u + 0x7fffu + ((u >> 16) & 1u)) >> 16;
  return (u16)r;
}
__device__ __forceinline__ float bf2f(u16 w) { return __uint_as_float(((u32)w) << 16); }

__global__ void k_cnt(const int* __restrict__ dst, int* __restrict__ cnt, int E) {
  int e = blockIdx.x * blockDim.x + threadIdx.x;
  if (e < E) atomicAdd(&cnt[dst[e]], 1);
}

// --- parallel scan: scan1 block sums -> scan2 scan of ~98 sums -> scan3 local scan ---
__global__ void k_scan1(const int* __restrict__ cnt, int* __restrict__ bsum, int N) {
  __shared__ int ws[4];
  int t = threadIdx.x;
  int i = blockIdx.x * 256 + t;
  int v = (i < N) ? cnt[i] : 0;
  int s = v;
  for (int off = 1; off < 64; off <<= 1) s += __shfl_xor(s, off);
  int wid = t >> 6, lane = t & 63;
  if (lane == 0) ws[wid] = s;
  __syncthreads();
  if (t == 0) bsum[blockIdx.x] = ws[0] + ws[1] + ws[2] + ws[3];
}

__global__ void k_scan2(int* __restrict__ bsum, int* __restrict__ row, int nb, int N) {
  __shared__ int s[256];
  int t = threadIdx.x;
  if (t < nb) s[t] = bsum[t];
  __syncthreads();
  if (t == 0) {
    int run = 0;
    for (int i = 0; i < nb; ++i) { int x = s[i]; s[i] = run; run += x; }
    row[N] = run;
  }
  __syncthreads();
  if (t < nb) bsum[t] = s[t];
}

__global__ void k_scan3(const int* __restrict__ cnt, const int* __restrict__ bsum,
                        int* __restrict__ row, int* __restrict__ cursor, int N) {
  __shared__ int ws[4];
  int t = threadIdx.x;
  int i = blockIdx.x * 256 + t;
  int v = (i < N) ? cnt[i] : 0;
  int lane = t & 63, wid = t >> 6;
  int incl = v;
  for (int off = 1; off < 64; off <<= 1) {
    int u = __shfl_up(incl, off);
    if (lane >= off) incl += u;
  }
  if (lane == 63) ws[wid] = incl;
  __syncthreads();
  int woff = bsum[blockIdx.x];
  for (int w = 0; w < wid; ++w) woff += ws[w];
  int excl = woff + incl - v;
  if (i < N) { row[i] = excl; cursor[i] = excl; }
}

// pos[e] = CSR slot of edge e (counting sort position among same-dst edges)
__global__ void k_pos(const int* __restrict__ dst, int* __restrict__ cursor,
                      int* __restrict__ pos, int E) {
  int e = blockIdx.x * blockDim.x + threadIdx.x;
  if (e < E) pos[e] = atomicAdd(&cursor[dst[e]], 1);
}

// hmid -> plain bf16; 2 edges/block, ea computed once in LDS
// [verified r18-r24: never appeared in top-5 counters; coalesced Ahi writes]
__global__ __launch_bounds__(256) void k_edge_mlp(
    const float* __restrict__ ea_in, const float* __restrict__ Wea,
    const float* __restrict__ bea, const float* __restrict__ We1,
    const float* __restrict__ be1, u16* __restrict__ Ahi, int E) {
  __shared__ float att[2][19];
  __shared__ float ea[2][12];
  int half = threadIdx.x >> 7;
  int t = threadIdx.x & 127;
  int e = blockIdx.x * 2 + half;
  bool real = (e < E);
  int ee = real ? e : E - 1;
  if (t < 19) att[half][t] = ea_in[(size_t)ee * 19 + t];
  __syncthreads();
  if (t < 12) {
    float a = bea[t];
#pragma unroll
    for (int k = 0; k < 19; ++k) a += att[half][k] * Wea[k * 12 + t];
    ea[half][t] = fmaxf(a, 0.0f);
  }
  __syncthreads();
  float a = be1[t];
#pragma unroll
  for (int j = 0; j < 12; ++j) a += ea[half][j] * We1[j * 128 + t];
  if (real) Ahi[(size_t)e * 128 + t] = f2bf(fmaxf(a, 0.0f));
}

// Fused prep (r24 config): node MLP + W_e2 pack + GRU packs + W_l1 pack.
// Edge MLP deliberately NOT fused (r26 counter-verified regression: tail-of-
// dispatch serial work + uncoalesced writes -> 2x write amplification).
__global__ void k_prep_all(
    const float* __restrict__ x, const float* __restrict__ Wn,
    const float* __restrict__ bn, float* __restrict__ h, int N, int nbNode,
    const float* __restrict__ W2, u16* __restrict__ Bph, int nbPack,
    const float* __restrict__ Wih, const float* __restrict__ Whh,
    u16* __restrict__ WpI, u16* __restrict__ WpH, int nbWtf,
    const float* __restrict__ Wl1, u16* __restrict__ Wp1) {
  int b = blockIdx.x;
  if (b < nbNode) {
    int tid = b * 256 + threadIdx.x;
    if (tid >= N * 64) return;
    int n = tid >> 6, f = tid & 63;
    float acc = bn[f];
    for (int k = 0; k < 8; ++k) acc += x[(size_t)n * 8 + k] * Wn[k * 64 + f];
    h[tid] = fmaxf(acc, 0.0f);
  } else if (b < nbNode + nbPack) {
    int tid = (b - nbNode) * 256 + threadIdx.x;
    if (tid >= 128 * 4096) return;
    int j = tid & 7;
    int lane = (tid >> 3) & 63;
    int nt = (tid >> 9) & 3;
    int ks = (tid >> 11) & 3;
    int d = tid >> 13;
    int c = lane & 15, q = lane >> 4;
    int k = ks * 32 + q * 8 + j;
    int n = d * 64 + nt * 16 + c;
    Bph[tid] = f2bf(W2[(size_t)k * 4096 + n]);
  } else if (b < nbNode + nbPack + nbWtf) {
    int tid = (b - nbNode - nbPack) * 256 + threadIdx.x;
    if (tid >= 2 * 12288) return;
    int w = tid / 12288;
    int r = tid - w * 12288;
    int jj = r & 7;
    int lane = (r >> 3) & 63;
    int t = r >> 9;
    int nt = t % 12, ks = t / 12;
    int c = lane & 15, q = lane >> 4;
    int j = nt * 16 + c;
    int k = ks * 32 + q * 8 + jj;
    const float* W = w ? Whh : Wih;
    u16* Wp = w ? WpH : WpI;
    Wp[r] = f2bf(W[j * 64 + k]);
  } else {
    int tid = (b - nbNode - nbPack - nbWtf) * 256 + threadIdx.x;
    if (tid >= 3 * 8 * 64 * 8) return;
    int j = tid & 7;
    int lane = (tid >> 3) & 63;
    int nt = (tid >> 9) & 7;
    int ks = tid >> 12;
    int c = lane & 15, q = lane >> 4;
    int k = ks * 32 + q * 8 + j;
    int n = nt * 16 + c;
    Wp1[tid] = f2bf((k < 72) ? Wl1[k * 128 + n] : 0.0f);
  }
}

// Fused conv, r27 = r24 structure (verified 74.2us) + hsT XOR-swizzle
// (swizzle verified r25/r26: write col = r ^ ((s&7)<<2), read ^ swz(dl)).
// LDS = 32768(Bdbuf) + 32768(hsT 64x128) + 8192(sb2h) = 73728 B -> 2 blk/CU.
__global__ __launch_bounds__(256, 2) void k_conv_fused(
    const u16* __restrict__ Ahi, const u16* __restrict__ Bph,
    const float* __restrict__ b2, const float* __restrict__ h,
    const int* __restrict__ src, const int* __restrict__ pos,
    u16* __restrict__ msgh, int E) {
  __shared__ __align__(16) u16 sB[2][8192];     // 2 x 16 KB B panels
  __shared__ __align__(16) float hsT[64 * 128]; // h[src[e], d] transposed+swizzled
  __shared__ __align__(16) u16 sb2h[4096];      // b2 as bf16
  int m0 = blockIdx.x * 128;
  int tid = threadIdx.x;
  int wave = tid >> 6, lane = tid & 63;
  int mw = wave >> 1, fw = wave & 1;
  int c = lane & 15, q = lane >> 4;

  auto stageB = [&](int d, int b) {
    const u16* gp = Bph + (size_t)d * 8192 + wave * 2048 + lane * 8;
    u16* lp = &sB[b][wave * 2048];
#pragma unroll
    for (int i = 0; i < 4; ++i)
      __builtin_amdgcn_global_load_lds(
          (const __attribute__((address_space(1))) unsigned int*)(gp + i * 512),
          (__attribute__((address_space(3))) unsigned int*)(lp + i * 512), 16, 0, 0);
  };

  stageB(0, 0);  // first panel in flight under the prologue

  // A fragments: 4 m-tiles x 4 k-slices, global->reg, held for whole kernel
  short8v afr[4][4];
#pragma unroll
  for (int mt = 0; mt < 4; ++mt) {
    int gr = m0 + mw * 64 + mt * 16 + c;
    if (gr >= E) gr = E - 1;
    const u16* ap = Ahi + (size_t)gr * 128 + q * 8;
#pragma unroll
    for (int ks = 0; ks < 4; ++ks) afr[mt][ks] = *(const short8v*)(ap + ks * 32);
  }

  // hsT: transposed+swizzled stage of h[src[e], 0:64]
#pragma unroll
  for (int p = 0; p < 8; ++p) {
    int slot = p * 256 + tid;
    int r = slot >> 4, s = slot & 15;  // edge r, d-quad s
    int ge = m0 + r;
    if (ge >= E) ge = E - 1;
    int sn = src[ge];
    float4 v = *(const float4*)(h + (size_t)sn * 64 + s * 4);
    int col = r ^ ((s & 7) << 2);
    hsT[(s * 4 + 0) * 128 + col] = v.x;
    hsT[(s * 4 + 1) * 128 + col] = v.y;
    hsT[(s * 4 + 2) * 128 + col] = v.z;
    hsT[(s * 4 + 3) * 128 + col] = v.w;
  }
  // sb2h: all 4096 b2 values as bf16
  {
    int t16 = tid * 16;
#pragma unroll
    for (int u = 0; u < 4; ++u) {
      float4 v = *(const float4*)(b2 + t16 + u * 4);
      sb2h[t16 + u * 4 + 0] = f2bf(v.x);
      sb2h[t16 + u * 4 + 1] = f2bf(v.y);
      sb2h[t16 + u * 4 + 2] = f2bf(v.z);
      sb2h[t16 + u * 4 + 3] = f2bf(v.w);
    }
  }
  __syncthreads();  // panel0 + hsT + sb2h ready

  float msg[4][2][4];
#pragma unroll
  for (int mt = 0; mt < 4; ++mt)
#pragma unroll
    for (int nt = 0; nt < 2; ++nt)
#pragma unroll
      for (int r = 0; r < 4; ++r) msg[mt][nt][r] = 0.0f;

  int cur = 0;
  for (int dl = 0; dl < 64; ++dl) {
    if (dl < 63) stageB(dl + 1, cur ^ 1);
    float b2v0 = bf2f(sb2h[dl * 64 + fw * 32 + c]);
    float b2v1 = bf2f(sb2h[dl * 64 + fw * 32 + 16 + c]);
    float4v acc[4][2];
#pragma unroll
    for (int mt = 0; mt < 4; ++mt)
#pragma unroll
      for (int nt = 0; nt < 2; ++nt) acc[mt][nt] = (float4v){0.f, 0.f, 0.f, 0.f};
    __builtin_amdgcn_s_setprio(1);
#pragma unroll
    for (int ks = 0; ks < 4; ++ks) {
      short8v b0 = *(const short8v*)(&sB[cur][ks * 2048 + fw * 1024 + lane * 8]);
      short8v b1 = *(const short8v*)(&sB[cur][ks * 2048 + fw * 1024 + 512 + lane * 8]);
#pragma unroll
      for (int mt = 0; mt < 4; ++mt) {
        acc[mt][0] = __builtin_amdgcn_mfma_f32_16x16x32_bf16(afr[mt][ks], b0, acc[mt][0], 0, 0, 0);
        acc[mt][1] = __builtin_amdgcn_mfma_f32_16x16x32_bf16(afr[mt][ks], b1, acc[mt][1], 0, 0, 0);
      }
    }
    __builtin_amdgcn_s_setprio(0);
    int swz = ((dl >> 2) & 7) << 2;
#pragma unroll
    for (int mt = 0; mt < 4; ++mt) {
      float4 hd4 = *(const float4*)(&hsT[dl * 128 + ((mw * 64 + mt * 16 + q * 4) ^ swz)]);
      float hd[4] = {hd4.x, hd4.y, hd4.z, hd4.w};
#pragma unroll
      for (int r = 0; r < 4; ++r) {
        msg[mt][0][r] += hd[r] * (acc[mt][0][r] + b2v0);
        msg[mt][1][r] += hd[r] * (acc[mt][1][r] + b2v1);
      }
    }
    __syncthreads();
    cur ^= 1;
  }

  // bf16 stores pre-permuted to CSR slot order: GRU reads contiguous rows
#pragma unroll
  for (int mt = 0; mt < 4; ++mt) {
#pragma unroll
    for (int r = 0; r < 4; ++r) {
      int e = m0 + mw * 64 + mt * 16 + q * 4 + r;
      if (e < E) {
        int pe = pos[e];
        u16* mp = msgh + (size_t)pe * 64 + fw * 32 + c;
        mp[0] = f2bf(msg[mt][0][r]);
        mp[16] = f2bf(msg[mt][1][r]);
      }
    }
  }
}

// MFMA GRU, r24: bf16 msgh gather   [verified r24]
__global__ __launch_bounds__(256, 2) void k_gru_mfma(
    const u16* __restrict__ msgh, const int* __restrict__ row,
    const float* __restrict__ cb, const u16* __restrict__ WpI,
    const u16* __restrict__ WpH, const float* __restrict__ bih,
    const float* __restrict__ bhh, const float* __restrict__ hin,
    float* __restrict__ hout, int N) {
  __shared__ __align__(16) u16 sM[64 * 72];
  __shared__ __align__(16) u16 sH[64 * 72];
  __shared__ __align__(16) float sHf[64 * 68];
  __shared__ int sRow[65];
  int n0 = blockIdx.x * 64;
  int tid = threadIdx.x;
  if (tid < 65) {
    int idx = n0 + tid;
    sRow[tid] = row[(idx <= N) ? idx : N];
  }
  __syncthreads();
  {
    int nl = tid >> 4, fq = tid & 15;
    float4 cbv = *(const float4*)(cb + fq * 4);
#pragma unroll
    for (int pass = 0; pass < 4; ++pass) {
      int n = pass * 16 + nl;
      int gn = n0 + n;
      bool real = (gn < N);
      int b0 = sRow[n], b1 = sRow[n + 1];
      if (!real) b1 = b0;
      float4 av = {0.f, 0.f, 0.f, 0.f};
      for (int j = b0; j < b1; ++j) {
        ushort4 mv = *(const ushort4*)(msgh + (size_t)j * 64 + fq * 4);
        av.x += bf2f(mv.x); av.y += bf2f(mv.y);
        av.z += bf2f(mv.z); av.w += bf2f(mv.w);
      }
      float cf = fmaxf((float)(b1 - b0), 1.0f);
      int hgn = real ? gn : N - 1;
      float4 hv = *(const float4*)(hin + (size_t)hgn * 64 + fq * 4);
      float m0v = fmaxf(av.x / cf + cbv.x, 0.0f);
      float m1v = fmaxf(av.y / cf + cbv.y, 0.0f);
      float m2v = fmaxf(av.z / cf + cbv.z, 0.0f);
      float m3v = fmaxf(av.w / cf + cbv.w, 0.0f);
      ushort4 mu; mu.x = f2bf(m0v); mu.y = f2bf(m1v); mu.z = f2bf(m2v); mu.w = f2bf(m3v);
      ushort4 hu; hu.x = f2bf(hv.x); hu.y = f2bf(hv.y); hu.z = f2bf(hv.z); hu.w = f2bf(hv.w);
      *(ushort4*)(&sM[n * 72 + fq * 4]) = mu;
      *(ushort4*)(&sH[n * 72 + fq * 4]) = hu;
      *(float4*)(&sHf[n * 68 + fq * 4]) = hv;
    }
  }
  __syncthreads();
  int wave = tid >> 6, lane = tid & 63;
  int c = lane & 15, q = lane >> 4;
  short8v am[2], ah[2];
#pragma unroll
  for (int ks = 0; ks < 2; ++ks) {
    am[ks] = *(const short8v*)(&sM[(wave * 16 + c) * 72 + ks * 32 + q * 8]);
    ah[ks] = *(const short8v*)(&sH[(wave * 16 + c) * 72 + ks * 32 + q * 8]);
  }
  float4v accRZ[8], accN[4], accHN[4];
#pragma unroll
  for (int i = 0; i < 8; ++i) accRZ[i] = (float4v){0.f, 0.f, 0.f, 0.f};
#pragma unroll
  for (int i = 0; i < 4; ++i) {
    accN[i] = (float4v){0.f, 0.f, 0.f, 0.f};
    accHN[i] = (float4v){0.f, 0.f, 0.f, 0.f};
  }
#pragma unroll
  for (int ks = 0; ks < 2; ++ks) {
#pragma unroll
    for (int nt = 0; nt < 8; ++nt) {
      short8v bI = *(const short8v*)(WpI + ((size_t)(ks * 12 + nt) * 64 + lane) * 8);
      short8v bH = *(const short8v*)(WpH + ((size_t)(ks * 12 + nt) * 64 + lane) * 8);
      accRZ[nt] = __builtin_amdgcn_mfma_f32_16x16x32_bf16(am[ks], bI, accRZ[nt], 0, 0, 0);
      accRZ[nt] = __builtin_amdgcn_mfma_f32_16x16x32_bf16(ah[ks], bH, accRZ[nt], 0, 0, 0);
    }
#pragma unroll
    for (int nt = 0; nt < 4; ++nt) {
      short8v bI = *(const short8v*)(WpI + ((size_t)(ks * 12 + 8 + nt) * 64 + lane) * 8);
      short8v bH = *(const short8v*)(WpH + ((size_t)(ks * 12 + 8 + nt) * 64 + lane) * 8);
      accN[nt] = __builtin_amdgcn_mfma_f32_16x16x32_bf16(am[ks], bI, accN[nt], 0, 0, 0);
      accHN[nt] = __builtin_amdgcn_mfma_f32_16x16x32_bf16(ah[ks], bH, accHN[nt], 0, 0, 0);
    }
  }
#pragma unroll
  for (int nt = 0; nt < 4; ++nt) {
    int f = nt * 16 + c;
    float brz_r = bih[f] + bhh[f];
    float brz_z = bih[64 + f] + bhh[64 + f];
    float bin = bih[128 + f];
    float bhn = bhh[128 + f];
#pragma unroll
    for (int r = 0; r < 4; ++r) {
      int nl = wave * 16 + q * 4 + r;
      int gn = n0 + nl;
      float rr = sigm(accRZ[nt][r] + brz_r);
      float zz = sigm(accRZ[nt + 4][r] + brz_z);
      float ng = tanhf(accN[nt][r] + bin + rr * (accHN[nt][r] + bhn));
      float hv = sHf[nl * 68 + f];
      if (gn < N) hout[(size_t)gn * 64 + f] = (1.0f - zz) * ng + zz * hv;
    }
  }
}

// MFMA final MLP, r23-vectorized staging   [verified r23/r24]
__global__ __launch_bounds__(256) void k_final_mfma(
    const float* __restrict__ h, const float* __restrict__ ea3,
    const int* __restrict__ idx3, const u16* __restrict__ Wp1,
    const float* __restrict__ bl1, const float* __restrict__ Wl2,
    const float* __restrict__ bl2, float* __restrict__ out, int E3) {
  __shared__ __align__(16) u16 sF[64 * 104];
  int e0 = blockIdx.x * 64;
  int tid = threadIdx.x;
  {
    int er = tid >> 2;
    int part = tid & 3;
    int ge = e0 + er;
    int gc = (ge < E3) ? ge : E3 - 1;
    int a = idx3[gc], b = idx3[E3 + gc];
    const float* pa = h + (size_t)a * 64 + part * 16;
    const float* pb = h + (size_t)b * 64 + part * 16;
#pragma unroll
    for (int u = 0; u < 4; ++u) {
      float4 va = *(const float4*)(pa + u * 4);
      float4 vb = *(const float4*)(pb + u * 4);
      ushort4 mu;
      mu.x = f2bf(0.5f * (va.x + vb.x));
      mu.y = f2bf(0.5f * (va.y + vb.y));
      mu.z = f2bf(0.5f * (va.z + vb.z));
      mu.w = f2bf(0.5f * (va.w + vb.w));
      *(ushort4*)(&sF[er * 104 + part * 16 + u * 4]) = mu;
    }
    if (part == 0) {
      float4 e0v = *(const float4*)(ea3 + (size_t)gc * 8);
      float4 e1v = *(const float4*)(ea3 + (size_t)gc * 8 + 4);
      ushort4 u0, u1;
      u0.x = f2bf(e0v.x); u0.y = f2bf(e0v.y); u0.z = f2bf(e0v.z); u0.w = f2bf(e0v.w);
      u1.x = f2bf(e1v.x); u1.y = f2bf(e1v.y); u1.z = f2bf(e1v.z); u1.w = f2bf(e1v.w);
      *(ushort4*)(&sF[er * 104 + 64]) = u0;
      *(ushort4*)(&sF[er * 104 + 68]) = u1;
    } else {
      ushort4 z = {0, 0, 0, 0};
      *(ushort4*)(&sF[er * 104 + 72 + (part - 1) * 8]) = z;
      *(ushort4*)(&sF[er * 104 + 76 + (part - 1) * 8]) = z;
    }
  }
  __syncthreads();
  int wave = tid >> 6, lane = tid & 63;
  int c = lane & 15, q = lane >> 4;
  float4v acc[8];
#pragma unroll
  for (int nt = 0; nt < 8; ++nt) acc[nt] = (float4v){0.f, 0.f, 0.f, 0.f};
#pragma unroll
  for (int ks = 0; ks < 3; ++ks) {
    short8v af = *(const short8v*)(&sF[(wave * 16 + c) * 104 + ks * 32 + q * 8]);
#pragma unroll
    for (int nt = 0; nt < 8; ++nt) {
      short8v bf = *(const short8v*)(Wp1 + ((size_t)(ks * 8 + nt) * 64 + lane) * 8);
      acc[nt] = __builtin_amdgcn_mfma_f32_16x16x32_bf16(af, bf, acc[nt], 0, 0, 0);
    }
  }
  float v[4] = {0.f, 0.f, 0.f, 0.f};
#pragma unroll
  for (int nt = 0; nt < 8; ++nt) {
    int n = nt * 16 + c;
    float b1 = bl1[n];
    float w2 = Wl2[n];
#pragma unroll
    for (int r = 0; r < 4; ++r) v[r] += fmaxf(acc[nt][r] + b1, 0.0f) * w2;
  }
#pragma unroll
  for (int off = 1; off < 16; off <<= 1) {
#pragma unroll
    for (int r = 0; r < 4; ++r) v[r] += __shfl_xor(v[r], off);
  }
  if (c == 0) {
    float b2v = bl2[0];
#pragma unroll
    for (int r = 0; r < 4; ++r) {
      int e = e0 + wave * 16 + q * 4 + r;
      if (e < E3) out[e] = v[r] + b2v;
    }
  }
}

extern "C" void kernel_launch(void* const* d_in, const int* in_sizes, int n_in,
                              void* d_out, int out_size, void* d_ws, size_t ws_size,
                              hipStream_t stream) {
  const float* x          = (const float*)d_in[0];
  const float* edge_attr  = (const float*)d_in[1];
  const float* edge_attr3 = (const float*)d_in[2];
  const int*   edge_index = (const int*)d_in[3];
  const int*   edge_index3= (const int*)d_in[4];
  const float* W_node = (const float*)d_in[5];
  const float* b_node = (const float*)d_in[6];
  const float* W_ea   = (const float*)d_in[7];
  const float* b_ea   = (const float*)d_in[8];
  const float* W_e1   = (const float*)d_in[9];
  const float* b_e1   = (const float*)d_in[10];
  const float* W_e2   = (const float*)d_in[11];
  const float* b_e2   = (const float*)d_in[12];
  const float* conv_bias = (const float*)d_in[13];
  const float* W_ih   = (const float*)d_in[14];
  const float* b_ih   = (const float*)d_in[15];
  const float* W_hh   = (const float*)d_in[16];
  const float* b_hh   = (const float*)d_in[17];
  const float* W_l1   = (const float*)d_in[18];
  const float* b_l1   = (const float*)d_in[19];
  const float* W_l2   = (const float*)d_in[20];
  const float* b_l2   = (const float*)d_in[21];

  int N  = in_sizes[0] / 8;
  int E  = in_sizes[1] / 19;
  int E3 = in_sizes[2] / 8;

  char* p = (char*)d_ws;
  auto carve = [&](size_t bytes) -> void* {
    char* q = p;
    p += (bytes + 255) & ~(size_t)255;
    return (void*)q;
  };
  float* hA    = (float*)carve((size_t)N * 64 * 4);
  float* hB    = (float*)carve((size_t)N * 64 * 4);
  u16*   msgh  = (u16*)carve((size_t)E * 64 * 2);
  int*   cnt   = (int*)carve((size_t)N * 4);
  int*   row   = (int*)carve((size_t)(N + 1) * 4);
  int*   cursor= (int*)carve((size_t)N * 4);
  int*   pos   = (int*)carve((size_t)E * 4);
  int*   bsum  = (int*)carve(256 * 4);
  u16*   Ahi   = (u16*)carve((size_t)E * 128 * 2);
  u16*   Bph   = (u16*)carve((size_t)128 * 4096 * 2);
  u16*   WpI   = (u16*)carve(12288 * 2);
  u16*   WpH   = (u16*)carve(12288 * 2);
  u16*   Wp1   = (u16*)carve(12288 * 2);

  const int* src = edge_index;
  const int* dst = edge_index + E;

  int nb = (N + 255) / 256;
  // CSR build (once)
  hipMemsetAsync(cnt, 0, (size_t)N * 4, stream);
  k_cnt<<<(E + 255) / 256, 256, 0, stream>>>(dst, cnt, E);
  k_scan1<<<nb, 256, 0, stream>>>(cnt, bsum, N);
  k_scan2<<<1, 256, 0, stream>>>(bsum, row, nb, N);
  k_scan3<<<nb, 256, 0, stream>>>(cnt, bsum, row, cursor, N);
  k_pos<<<(E + 255) / 256, 256, 0, stream>>>(dst, cursor, pos, E);

  k_edge_mlp<<<(E + 1) / 2, 256, 0, stream>>>(edge_attr, W_ea, b_ea, W_e1, b_e1, Ahi, E);
  int nbNode = ((size_t)N * 64 + 255) / 256;
  int nbPack = (128 * 4096 + 255) / 256;
  int nbWtf  = (2 * 12288 + 255) / 256;
  int nbWl1  = (12288 + 255) / 256;
  k_prep_all<<<nbNode + nbPack + nbWtf + nbWl1, 256, 0, stream>>>(
      x, W_node, b_node, hA, N, nbNode, W_e2, Bph, nbPack,
      W_ih, W_hh, WpI, WpH, nbWtf, W_l1, Wp1);

  float* hcur = hA;
  float* hnxt = hB;
  int gconv = (E + 127) / 128;
  int ngru = (N + 63) / 64;
  for (int it = 0; it < 3; ++it) {
    k_conv_fused<<<gconv, 256, 0, stream>>>(Ahi, Bph, b_e2, hcur, src, pos, msgh, E);
    k_gru_mfma<<<ngru, 256, 0, stream>>>(msgh, row, conv_bias, WpI, WpH,
                                         b_ih, b_hh, hcur, hnxt, N);
    float* tmp = hcur; hcur = hnxt; hnxt = tmp;
  }
  k_final_mfma<<<(E3 + 63) / 64, 256, 0, stream>>>(hcur, edge_attr3, edge_index3, Wp1,
                                                   b_l1, W_l2, b_l2, (float*)d_out, E3);
}

// Round 10
// 392.599 us; speedup vs baseline: 1.2943x; 1.0231x over previous
//
#include <hip/hip_runtime.h>

typedef unsigned short u16;
typedef unsigned int u32;
typedef __attribute__((ext_vector_type(8))) short short8v;
typedef __attribute__((ext_vector_type(4))) float float4v;

__device__ __forceinline__ float sigm(float x) { return 1.0f / (1.0f + __expf(-x)); }
__device__ __forceinline__ u16 f2bf(float f) {
  u32 u = __float_as_uint(f);
  u32 r = (u + 0x7fffu + ((u >> 16) & 1u)) >> 16;
  return (u16)r;
}
__device__ __forceinline__ float bf2f(u16 w) { return __uint_as_float(((u32)w) << 16); }

__global__ void k_cnt(const int* __restrict__ dst, int* __restrict__ cnt, int E) {
  int e = blockIdx.x * blockDim.x + threadIdx.x;
  if (e < E) atomicAdd(&cnt[dst[e]], 1);
}

// --- parallel scan: scan1 block sums -> scan2 scan of ~98 sums -> scan3 local scan ---
__global__ void k_scan1(const int* __restrict__ cnt, int* __restrict__ bsum, int N) {
  __shared__ int ws[4];
  int t = threadIdx.x;
  int i = blockIdx.x * 256 + t;
  int v = (i < N) ? cnt[i] : 0;
  int s = v;
  for (int off = 1; off < 64; off <<= 1) s += __shfl_xor(s, off);
  int wid = t >> 6, lane = t & 63;
  if (lane == 0) ws[wid] = s;
  __syncthreads();
  if (t == 0) bsum[blockIdx.x] = ws[0] + ws[1] + ws[2] + ws[3];
}

__global__ void k_scan2(int* __restrict__ bsum, int* __restrict__ row, int nb, int N) {
  __shared__ int s[256];
  int t = threadIdx.x;
  if (t < nb) s[t] = bsum[t];
  __syncthreads();
  if (t == 0) {
    int run = 0;
    for (int i = 0; i < nb; ++i) { int x = s[i]; s[i] = run; run += x; }
    row[N] = run;
  }
  __syncthreads();
  if (t < nb) bsum[t] = s[t];
}

__global__ void k_scan3(const int* __restrict__ cnt, const int* __restrict__ bsum,
                        int* __restrict__ row, int* __restrict__ cursor, int N) {
  __shared__ int ws[4];
  int t = threadIdx.x;
  int i = blockIdx.x * 256 + t;
  int v = (i < N) ? cnt[i] : 0;
  int lane = t & 63, wid = t >> 6;
  int incl = v;
  for (int off = 1; off < 64; off <<= 1) {
    int u = __shfl_up(incl, off);
    if (lane >= off) incl += u;
  }
  if (lane == 63) ws[wid] = incl;
  __syncthreads();
  int woff = bsum[blockIdx.x];
  for (int w = 0; w < wid; ++w) woff += ws[w];
  int excl = woff + incl - v;
  if (i < N) { row[i] = excl; cursor[i] = excl; }
}

// pos[e] = CSR slot of edge e (counting sort position among same-dst edges)
__global__ void k_pos(const int* __restrict__ dst, int* __restrict__ cursor,
                      int* __restrict__ pos, int E) {
  int e = blockIdx.x * blockDim.x + threadIdx.x;
  if (e < E) pos[e] = atomicAdd(&cursor[dst[e]], 1);
}

// hmid -> plain bf16; 2 edges/block, ea computed once in LDS
// [verified r18-r24: never appeared in top-5 counters; coalesced Ahi writes]
__global__ __launch_bounds__(256) void k_edge_mlp(
    const float* __restrict__ ea_in, const float* __restrict__ Wea,
    const float* __restrict__ bea, const float* __restrict__ We1,
    const float* __restrict__ be1, u16* __restrict__ Ahi, int E) {
  __shared__ float att[2][19];
  __shared__ float ea[2][12];
  int half = threadIdx.x >> 7;
  int t = threadIdx.x & 127;
  int e = blockIdx.x * 2 + half;
  bool real = (e < E);
  int ee = real ? e : E - 1;
  if (t < 19) att[half][t] = ea_in[(size_t)ee * 19 + t];
  __syncthreads();
  if (t < 12) {
    float a = bea[t];
#pragma unroll
    for (int k = 0; k < 19; ++k) a += att[half][k] * Wea[k * 12 + t];
    ea[half][t] = fmaxf(a, 0.0f);
  }
  __syncthreads();
  float a = be1[t];
#pragma unroll
  for (int j = 0; j < 12; ++j) a += ea[half][j] * We1[j * 128 + t];
  if (real) Ahi[(size_t)e * 128 + t] = f2bf(fmaxf(a, 0.0f));
}

// Fused prep (r24 config): node MLP (h -> bf16 now) + W_e2 pack + GRU packs + W_l1 pack.
__global__ void k_prep_all(
    const float* __restrict__ x, const float* __restrict__ Wn,
    const float* __restrict__ bn, u16* __restrict__ hbf, int N, int nbNode,
    const float* __restrict__ W2, u16* __restrict__ Bph, int nbPack,
    const float* __restrict__ Wih, const float* __restrict__ Whh,
    u16* __restrict__ WpI, u16* __restrict__ WpH, int nbWtf,
    const float* __restrict__ Wl1, u16* __restrict__ Wp1) {
  int b = blockIdx.x;
  if (b < nbNode) {
    int tid = b * 256 + threadIdx.x;
    if (tid >= N * 64) return;
    int n = tid >> 6, f = tid & 63;
    float acc = bn[f];
    for (int k = 0; k < 8; ++k) acc += x[(size_t)n * 8 + k] * Wn[k * 64 + f];
    hbf[tid] = f2bf(fmaxf(acc, 0.0f));
  } else if (b < nbNode + nbPack) {
    int tid = (b - nbNode) * 256 + threadIdx.x;
    if (tid >= 128 * 4096) return;
    int j = tid & 7;
    int lane = (tid >> 3) & 63;
    int nt = (tid >> 9) & 3;
    int ks = (tid >> 11) & 3;
    int d = tid >> 13;
    int c = lane & 15, q = lane >> 4;
    int k = ks * 32 + q * 8 + j;
    int n = d * 64 + nt * 16 + c;
    Bph[tid] = f2bf(W2[(size_t)k * 4096 + n]);
  } else if (b < nbNode + nbPack + nbWtf) {
    int tid = (b - nbNode - nbPack) * 256 + threadIdx.x;
    if (tid >= 2 * 12288) return;
    int w = tid / 12288;
    int r = tid - w * 12288;
    int jj = r & 7;
    int lane = (r >> 3) & 63;
    int t = r >> 9;
    int nt = t % 12, ks = t / 12;
    int c = lane & 15, q = lane >> 4;
    int j = nt * 16 + c;
    int k = ks * 32 + q * 8 + jj;
    const float* W = w ? Whh : Wih;
    u16* Wp = w ? WpH : WpI;
    Wp[r] = f2bf(W[j * 64 + k]);
  } else {
    int tid = (b - nbNode - nbPack - nbWtf) * 256 + threadIdx.x;
    if (tid >= 3 * 8 * 64 * 8) return;
    int j = tid & 7;
    int lane = (tid >> 3) & 63;
    int nt = (tid >> 9) & 7;
    int ks = tid >> 12;
    int c = lane & 15, q = lane >> 4;
    int k = ks * 32 + q * 8 + j;
    int n = nt * 16 + c;
    Wp1[tid] = f2bf((k < 72) ? Wl1[k * 128 + n] : 0.0f);
  }
}

// Fused conv, r28 = r24 structure EXACTLY (verified best, 74.2us; swizzle
// reverted per r27 counter-verdict: conflicts were 1.6% of cycles, XOR math
// cost more). Only change: h gathered as bf16 (halves h fetch stream).
// LDS = 32768(Bdbuf) + 33792(hsT 64x132 f32) + 8192(sb2h) = 74752 B -> 2 blk/CU.
__global__ __launch_bounds__(256, 2) void k_conv_fused(
    const u16* __restrict__ Ahi, const u16* __restrict__ Bph,
    const float* __restrict__ b2, const u16* __restrict__ hbf,
    const int* __restrict__ src, const int* __restrict__ pos,
    u16* __restrict__ msgh, int E) {
  __shared__ __align__(16) u16 sB[2][8192];     // 2 x 16 KB B panels
  __shared__ __align__(16) float hsT[64 * 132]; // h[src[e], d] transposed: [d][edge]
  __shared__ __align__(16) u16 sb2h[4096];      // b2 as bf16
  int m0 = blockIdx.x * 128;
  int tid = threadIdx.x;
  int wave = tid >> 6, lane = tid & 63;
  int mw = wave >> 1, fw = wave & 1;
  int c = lane & 15, q = lane >> 4;

  auto stageB = [&](int d, int b) {
    const u16* gp = Bph + (size_t)d * 8192 + wave * 2048 + lane * 8;
    u16* lp = &sB[b][wave * 2048];
#pragma unroll
    for (int i = 0; i < 4; ++i)
      __builtin_amdgcn_global_load_lds(
          (const __attribute__((address_space(1))) unsigned int*)(gp + i * 512),
          (__attribute__((address_space(3))) unsigned int*)(lp + i * 512), 16, 0, 0);
  };

  stageB(0, 0);  // first panel in flight under the prologue

  // A fragments: 4 m-tiles x 4 k-slices, global->reg, held for whole kernel
  short8v afr[4][4];
#pragma unroll
  for (int mt = 0; mt < 4; ++mt) {
    int gr = m0 + mw * 64 + mt * 16 + c;
    if (gr >= E) gr = E - 1;
    const u16* ap = Ahi + (size_t)gr * 128 + q * 8;
#pragma unroll
    for (int ks = 0; ks < 4; ++ks) afr[mt][ks] = *(const short8v*)(ap + ks * 32);
  }

  // hsT: transposed stage of h[src[e], 0:64] (bf16 global -> f32 LDS)
#pragma unroll
  for (int p = 0; p < 8; ++p) {
    int slot = p * 256 + tid;
    int r = slot >> 4, s = slot & 15;  // edge r, d-quad s
    int ge = m0 + r;
    if (ge >= E) ge = E - 1;
    int sn = src[ge];
    ushort4 v = *(const ushort4*)(hbf + (size_t)sn * 64 + s * 4);
    hsT[(s * 4 + 0) * 132 + r] = bf2f(v.x);
    hsT[(s * 4 + 1) * 132 + r] = bf2f(v.y);
    hsT[(s * 4 + 2) * 132 + r] = bf2f(v.z);
    hsT[(s * 4 + 3) * 132 + r] = bf2f(v.w);
  }
  // sb2h: all 4096 b2 values as bf16
  {
    int t16 = tid * 16;
#pragma unroll
    for (int u = 0; u < 4; ++u) {
      float4 v = *(const float4*)(b2 + t16 + u * 4);
      sb2h[t16 + u * 4 + 0] = f2bf(v.x);
      sb2h[t16 + u * 4 + 1] = f2bf(v.y);
      sb2h[t16 + u * 4 + 2] = f2bf(v.z);
      sb2h[t16 + u * 4 + 3] = f2bf(v.w);
    }
  }
  __syncthreads();  // panel0 + hsT + sb2h ready

  float msg[4][2][4];
#pragma unroll
  for (int mt = 0; mt < 4; ++mt)
#pragma unroll
    for (int nt = 0; nt < 2; ++nt)
#pragma unroll
      for (int r = 0; r < 4; ++r) msg[mt][nt][r] = 0.0f;

  int cur = 0;
  for (int dl = 0; dl < 64; ++dl) {
    if (dl < 63) stageB(dl + 1, cur ^ 1);
    float b2v0 = bf2f(sb2h[dl * 64 + fw * 32 + c]);
    float b2v1 = bf2f(sb2h[dl * 64 + fw * 32 + 16 + c]);
    float4v acc[4][2];
#pragma unroll
    for (int mt = 0; mt < 4; ++mt)
#pragma unroll
      for (int nt = 0; nt < 2; ++nt) acc[mt][nt] = (float4v){0.f, 0.f, 0.f, 0.f};
    __builtin_amdgcn_s_setprio(1);
#pragma unroll
    for (int ks = 0; ks < 4; ++ks) {
      short8v b0 = *(const short8v*)(&sB[cur][ks * 2048 + fw * 1024 + lane * 8]);
      short8v b1 = *(const short8v*)(&sB[cur][ks * 2048 + fw * 1024 + 512 + lane * 8]);
#pragma unroll
      for (int mt = 0; mt < 4; ++mt) {
        acc[mt][0] = __builtin_amdgcn_mfma_f32_16x16x32_bf16(afr[mt][ks], b0, acc[mt][0], 0, 0, 0);
        acc[mt][1] = __builtin_amdgcn_mfma_f32_16x16x32_bf16(afr[mt][ks], b1, acc[mt][1], 0, 0, 0);
      }
    }
    __builtin_amdgcn_s_setprio(0);
#pragma unroll
    for (int mt = 0; mt < 4; ++mt) {
      float4 hd4 = *(const float4*)(&hsT[dl * 132 + mw * 64 + mt * 16 + q * 4]);
      float hd[4] = {hd4.x, hd4.y, hd4.z, hd4.w};
#pragma unroll
      for (int r = 0; r < 4; ++r) {
        msg[mt][0][r] += hd[r] * (acc[mt][0][r] + b2v0);
        msg[mt][1][r] += hd[r] * (acc[mt][1][r] + b2v1);
      }
    }
    __syncthreads();
    cur ^= 1;
  }

  // bf16 stores pre-permuted to CSR slot order: GRU reads contiguous rows
#pragma unroll
  for (int mt = 0; mt < 4; ++mt) {
#pragma unroll
    for (int r = 0; r < 4; ++r) {
      int e = m0 + mw * 64 + mt * 16 + q * 4 + r;
      if (e < E) {
        int pe = pos[e];
        u16* mp = msgh + (size_t)pe * 64 + fw * 32 + c;
        mp[0] = f2bf(msg[mt][0][r]);
        mp[16] = f2bf(msg[mt][1][r]);
      }
    }
  }
}

// MFMA GRU, r28: bf16 msgh gather + bf16 hin/hout (internal math f32).
// Traffic 19.5 -> 13 MB/dispatch.
__global__ __launch_bounds__(256, 2) void k_gru_mfma(
    const u16* __restrict__ msgh, const int* __restrict__ row,
    const float* __restrict__ cb, const u16* __restrict__ WpI,
    const u16* __restrict__ WpH, const float* __restrict__ bih,
    const float* __restrict__ bhh, const u16* __restrict__ hin,
    u16* __restrict__ hout, int N) {
  __shared__ __align__(16) u16 sM[64 * 72];
  __shared__ __align__(16) u16 sH[64 * 72];
  __shared__ __align__(16) float sHf[64 * 68];
  __shared__ int sRow[65];
  int n0 = blockIdx.x * 64;
  int tid = threadIdx.x;
  if (tid < 65) {
    int idx = n0 + tid;
    sRow[tid] = row[(idx <= N) ? idx : N];
  }
  __syncthreads();
  {
    int nl = tid >> 4, fq = tid & 15;
    float4 cbv = *(const float4*)(cb + fq * 4);
#pragma unroll
    for (int pass = 0; pass < 4; ++pass) {
      int n = pass * 16 + nl;
      int gn = n0 + n;
      bool real = (gn < N);
      int b0 = sRow[n], b1 = sRow[n + 1];
      if (!real) b1 = b0;
      float4 av = {0.f, 0.f, 0.f, 0.f};
      for (int j = b0; j < b1; ++j) {
        ushort4 mv = *(const ushort4*)(msgh + (size_t)j * 64 + fq * 4);
        av.x += bf2f(mv.x); av.y += bf2f(mv.y);
        av.z += bf2f(mv.z); av.w += bf2f(mv.w);
      }
      float cf = fmaxf((float)(b1 - b0), 1.0f);
      int hgn = real ? gn : N - 1;
      ushort4 hv = *(const ushort4*)(hin + (size_t)hgn * 64 + fq * 4);
      float hx = bf2f(hv.x), hy = bf2f(hv.y), hz = bf2f(hv.z), hw = bf2f(hv.w);
      float m0v = fmaxf(av.x / cf + cbv.x, 0.0f);
      float m1v = fmaxf(av.y / cf + cbv.y, 0.0f);
      float m2v = fmaxf(av.z / cf + cbv.z, 0.0f);
      float m3v = fmaxf(av.w / cf + cbv.w, 0.0f);
      ushort4 mu; mu.x = f2bf(m0v); mu.y = f2bf(m1v); mu.z = f2bf(m2v); mu.w = f2bf(m3v);
      *(ushort4*)(&sM[n * 72 + fq * 4]) = mu;
      *(ushort4*)(&sH[n * 72 + fq * 4]) = hv;  // already bf16
      float4 hf = {hx, hy, hz, hw};
      *(float4*)(&sHf[n * 68 + fq * 4]) = hf;
    }
  }
  __syncthreads();
  int wave = tid >> 6, lane = tid & 63;
  int c = lane & 15, q = lane >> 4;
  short8v am[2], ah[2];
#pragma unroll
  for (int ks = 0; ks < 2; ++ks) {
    am[ks] = *(const short8v*)(&sM[(wave * 16 + c) * 72 + ks * 32 + q * 8]);
    ah[ks] = *(const short8v*)(&sH[(wave * 16 + c) * 72 + ks * 32 + q * 8]);
  }
  float4v accRZ[8], accN[4], accHN[4];
#pragma unroll
  for (int i = 0; i < 8; ++i) accRZ[i] = (float4v){0.f, 0.f, 0.f, 0.f};
#pragma unroll
  for (int i = 0; i < 4; ++i) {
    accN[i] = (float4v){0.f, 0.f, 0.f, 0.f};
    accHN[i] = (float4v){0.f, 0.f, 0.f, 0.f};
  }
#pragma unroll
  for (int ks = 0; ks < 2; ++ks) {
#pragma unroll
    for (int nt = 0; nt < 8; ++nt) {
      short8v bI = *(const short8v*)(WpI + ((size_t)(ks * 12 + nt) * 64 + lane) * 8);
      short8v bH = *(const short8v*)(WpH + ((size_t)(ks * 12 + nt) * 64 + lane) * 8);
      accRZ[nt] = __builtin_amdgcn_mfma_f32_16x16x32_bf16(am[ks], bI, accRZ[nt], 0, 0, 0);
      accRZ[nt] = __builtin_amdgcn_mfma_f32_16x16x32_bf16(ah[ks], bH, accRZ[nt], 0, 0, 0);
    }
#pragma unroll
    for (int nt = 0; nt < 4; ++nt) {
      short8v bI = *(const short8v*)(WpI + ((size_t)(ks * 12 + 8 + nt) * 64 + lane) * 8);
      short8v bH = *(const short8v*)(WpH + ((size_t)(ks * 12 + 8 + nt) * 64 + lane) * 8);
      accN[nt] = __builtin_amdgcn_mfma_f32_16x16x32_bf16(am[ks], bI, accN[nt], 0, 0, 0);
      accHN[nt] = __builtin_amdgcn_mfma_f32_16x16x32_bf16(ah[ks], bH, accHN[nt], 0, 0, 0);
    }
  }
#pragma unroll
  for (int nt = 0; nt < 4; ++nt) {
    int f = nt * 16 + c;
    float brz_r = bih[f] + bhh[f];
    float brz_z = bih[64 + f] + bhh[64 + f];
    float bin = bih[128 + f];
    float bhn = bhh[128 + f];
#pragma unroll
    for (int r = 0; r < 4; ++r) {
      int nl = wave * 16 + q * 4 + r;
      int gn = n0 + nl;
      float rr = sigm(accRZ[nt][r] + brz_r);
      float zz = sigm(accRZ[nt + 4][r] + brz_z);
      float ng = tanhf(accN[nt][r] + bin + rr * (accHN[nt][r] + bhn));
      float hv = sHf[nl * 68 + f];
      if (gn < N) hout[(size_t)gn * 64 + f] = f2bf((1.0f - zz) * ng + zz * hv);
    }
  }
}

// MFMA final MLP, r28: bf16 h gather (halves the 20 MB h-pair stream).
__global__ __launch_bounds__(256) void k_final_mfma(
    const u16* __restrict__ hbf, const float* __restrict__ ea3,
    const int* __restrict__ idx3, const u16* __restrict__ Wp1,
    const float* __restrict__ bl1, const float* __restrict__ Wl2,
    const float* __restrict__ bl2, float* __restrict__ out, int E3) {
  __shared__ __align__(16) u16 sF[64 * 104];
  int e0 = blockIdx.x * 64;
  int tid = threadIdx.x;
  {
    int er = tid >> 2;
    int part = tid & 3;
    int ge = e0 + er;
    int gc = (ge < E3) ? ge : E3 - 1;
    int a = idx3[gc], b = idx3[E3 + gc];
    const u16* pa = hbf + (size_t)a * 64 + part * 16;
    const u16* pb = hbf + (size_t)b * 64 + part * 16;
#pragma unroll
    for (int u = 0; u < 2; ++u) {
      short8v va = *(const short8v*)(pa + u * 8);
      short8v vb = *(const short8v*)(pb + u * 8);
      short8v mu;
#pragma unroll
      for (int i = 0; i < 8; ++i)
        mu[i] = (short)f2bf(0.5f * (bf2f((u16)va[i]) + bf2f((u16)vb[i])));
      *(short8v*)(&sF[er * 104 + part * 16 + u * 8]) = mu;
    }
    if (part == 0) {
      float4 e0v = *(const float4*)(ea3 + (size_t)gc * 8);
      float4 e1v = *(const float4*)(ea3 + (size_t)gc * 8 + 4);
      ushort4 u0, u1;
      u0.x = f2bf(e0v.x); u0.y = f2bf(e0v.y); u0.z = f2bf(e0v.z); u0.w = f2bf(e0v.w);
      u1.x = f2bf(e1v.x); u1.y = f2bf(e1v.y); u1.z = f2bf(e1v.z); u1.w = f2bf(e1v.w);
      *(ushort4*)(&sF[er * 104 + 64]) = u0;
      *(ushort4*)(&sF[er * 104 + 68]) = u1;
    } else {
      ushort4 z = {0, 0, 0, 0};
      *(ushort4*)(&sF[er * 104 + 72 + (part - 1) * 8]) = z;
      *(ushort4*)(&sF[er * 104 + 76 + (part - 1) * 8]) = z;
    }
  }
  __syncthreads();
  int wave = tid >> 6, lane = tid & 63;
  int c = lane & 15, q = lane >> 4;
  float4v acc[8];
#pragma unroll
  for (int nt = 0; nt < 8; ++nt) acc[nt] = (float4v){0.f, 0.f, 0.f, 0.f};
#pragma unroll
  for (int ks = 0; ks < 3; ++ks) {
    short8v af = *(const short8v*)(&sF[(wave * 16 + c) * 104 + ks * 32 + q * 8]);
#pragma unroll
    for (int nt = 0; nt < 8; ++nt) {
      short8v bf = *(const short8v*)(Wp1 + ((size_t)(ks * 8 + nt) * 64 + lane) * 8);
      acc[nt] = __builtin_amdgcn_mfma_f32_16x16x32_bf16(af, bf, acc[nt], 0, 0, 0);
    }
  }
  float v[4] = {0.f, 0.f, 0.f, 0.f};
#pragma unroll
  for (int nt = 0; nt < 8; ++nt) {
    int n = nt * 16 + c;
    float b1 = bl1[n];
    float w2 = Wl2[n];
#pragma unroll
    for (int r = 0; r < 4; ++r) v[r] += fmaxf(acc[nt][r] + b1, 0.0f) * w2;
  }
#pragma unroll
  for (int off = 1; off < 16; off <<= 1) {
#pragma unroll
    for (int r = 0; r < 4; ++r) v[r] += __shfl_xor(v[r], off);
  }
  if (c == 0) {
    float b2v = bl2[0];
#pragma unroll
    for (int r = 0; r < 4; ++r) {
      int e = e0 + wave * 16 + q * 4 + r;
      if (e < E3) out[e] = v[r] + b2v;
    }
  }
}

extern "C" void kernel_launch(void* const* d_in, const int* in_sizes, int n_in,
                              void* d_out, int out_size, void* d_ws, size_t ws_size,
                              hipStream_t stream) {
  const float* x          = (const float*)d_in[0];
  const float* edge_attr  = (const float*)d_in[1];
  const float* edge_attr3 = (const float*)d_in[2];
  const int*   edge_index = (const int*)d_in[3];
  const int*   edge_index3= (const int*)d_in[4];
  const float* W_node = (const float*)d_in[5];
  const float* b_node = (const float*)d_in[6];
  const float* W_ea   = (const float*)d_in[7];
  const float* b_ea   = (const float*)d_in[8];
  const float* W_e1   = (const float*)d_in[9];
  const float* b_e1   = (const float*)d_in[10];
  const float* W_e2   = (const float*)d_in[11];
  const float* b_e2   = (const float*)d_in[12];
  const float* conv_bias = (const float*)d_in[13];
  const float* W_ih   = (const float*)d_in[14];
  const float* b_ih   = (const float*)d_in[15];
  const float* W_hh   = (const float*)d_in[16];
  const float* b_hh   = (const float*)d_in[17];
  const float* W_l1   = (const float*)d_in[18];
  const float* b_l1   = (const float*)d_in[19];
  const float* W_l2   = (const float*)d_in[20];
  const float* b_l2   = (const float*)d_in[21];

  int N  = in_sizes[0] / 8;
  int E  = in_sizes[1] / 19;
  int E3 = in_sizes[2] / 8;

  char* p = (char*)d_ws;
  auto carve = [&](size_t bytes) -> void* {
    char* q = p;
    p += (bytes + 255) & ~(size_t)255;
    return (void*)q;
  };
  u16*   hA    = (u16*)carve((size_t)N * 64 * 2);
  u16*   hB    = (u16*)carve((size_t)N * 64 * 2);
  u16*   msgh  = (u16*)carve((size_t)E * 64 * 2);
  int*   cnt   = (int*)carve((size_t)N * 4);
  int*   row   = (int*)carve((size_t)(N + 1) * 4);
  int*   cursor= (int*)carve((size_t)N * 4);
  int*   pos   = (int*)carve((size_t)E * 4);
  int*   bsum  = (int*)carve(256 * 4);
  u16*   Ahi   = (u16*)carve((size_t)E * 128 * 2);
  u16*   Bph   = (u16*)carve((size_t)128 * 4096 * 2);
  u16*   WpI   = (u16*)carve(12288 * 2);
  u16*   WpH   = (u16*)carve(12288 * 2);
  u16*   Wp1   = (u16*)carve(12288 * 2);

  const int* src = edge_index;
  const int* dst = edge_index + E;

  int nb = (N + 255) / 256;
  // CSR build (once)
  hipMemsetAsync(cnt, 0, (size_t)N * 4, stream);
  k_cnt<<<(E + 255) / 256, 256, 0, stream>>>(dst, cnt, E);
  k_scan1<<<nb, 256, 0, stream>>>(cnt, bsum, N);
  k_scan2<<<1, 256, 0, stream>>>(bsum, row, nb, N);
  k_scan3<<<nb, 256, 0, stream>>>(cnt, bsum, row, cursor, N);
  k_pos<<<(E + 255) / 256, 256, 0, stream>>>(dst, cursor, pos, E);

  k_edge_mlp<<<(E + 1) / 2, 256, 0, stream>>>(edge_attr, W_ea, b_ea, W_e1, b_e1, Ahi, E);
  int nbNode = ((size_t)N * 64 + 255) / 256;
  int nbPack = (128 * 4096 + 255) / 256;
  int nbWtf  = (2 * 12288 + 255) / 256;
  int nbWl1  = (12288 + 255) / 256;
  k_prep_all<<<nbNode + nbPack + nbWtf + nbWl1, 256, 0, stream>>>(
      x, W_node, b_node, hA, N, nbNode, W_e2, Bph, nbPack,
      W_ih, W_hh, WpI, WpH, nbWtf, W_l1, Wp1);

  u16* hcur = hA;
  u16* hnxt = hB;
  int gconv = (E + 127) / 128;
  int ngru = (N + 63) / 64;
  for (int it = 0; it < 3; ++it) {
    k_conv_fused<<<gconv, 256, 0, stream>>>(Ahi, Bph, b_e2, hcur, src, pos, msgh, E);
    k_gru_mfma<<<ngru, 256, 0, stream>>>(msgh, row, conv_bias, WpI, WpH,
                                         b_ih, b_hh, hcur, hnxt, N);
    u16* tmp = hcur; hcur = hnxt; hnxt = tmp;
  }
  k_final_mfma<<<(E3 + 63) / 64, 256, 0, stream>>>(hcur, edge_attr3, edge_index3, Wp1,
                                                   b_l1, W_l2, b_l2, (float*)d_out, E3);
}

// Round 11
// 388.128 us; speedup vs baseline: 1.3092x; 1.0115x over previous
//
#include <hip/hip_runtime.h>

typedef unsigned short u16;
typedef unsigned int u32;
typedef __attribute__((ext_vector_type(8))) short short8v;
typedef __attribute__((ext_vector_type(4))) float float4v;

__device__ __forceinline__ float sigm(float x) { return 1.0f / (1.0f + __expf(-x)); }
__device__ __forceinline__ u16 f2bf(float f) {
  u32 u = __float_as_uint(f);
  u32 r = (u + 0x7fffu + ((u >> 16) & 1u)) >> 16;
  return (u16)r;
}
__device__ __forceinline__ float bf2f(u16 w) { return __uint_as_float(((u32)w) << 16); }

__global__ void k_cnt(const int* __restrict__ dst, int* __restrict__ cnt, int E) {
  int e = blockIdx.x * blockDim.x + threadIdx.x;
  if (e < E) atomicAdd(&cnt[dst[e]], 1);
}

// --- parallel scan: scan1 block sums -> scan2 scan of ~98 sums -> scan3 local scan ---
__global__ void k_scan1(const int* __restrict__ cnt, int* __restrict__ bsum, int N) {
  __shared__ int ws[4];
  int t = threadIdx.x;
  int i = blockIdx.x * 256 + t;
  int v = (i < N) ? cnt[i] : 0;
  int s = v;
  for (int off = 1; off < 64; off <<= 1) s += __shfl_xor(s, off);
  int wid = t >> 6, lane = t & 63;
  if (lane == 0) ws[wid] = s;
  __syncthreads();
  if (t == 0) bsum[blockIdx.x] = ws[0] + ws[1] + ws[2] + ws[3];
}

__global__ void k_scan2(int* __restrict__ bsum, int* __restrict__ row, int nb, int N) {
  __shared__ int s[256];
  int t = threadIdx.x;
  if (t < nb) s[t] = bsum[t];
  __syncthreads();
  if (t == 0) {
    int run = 0;
    for (int i = 0; i < nb; ++i) { int x = s[i]; s[i] = run; run += x; }
    row[N] = run;
  }
  __syncthreads();
  if (t < nb) bsum[t] = s[t];
}

__global__ void k_scan3(const int* __restrict__ cnt, const int* __restrict__ bsum,
                        int* __restrict__ row, int* __restrict__ cursor, int N) {
  __shared__ int ws[4];
  int t = threadIdx.x;
  int i = blockIdx.x * 256 + t;
  int v = (i < N) ? cnt[i] : 0;
  int lane = t & 63, wid = t >> 6;
  int incl = v;
  for (int off = 1; off < 64; off <<= 1) {
    int u = __shfl_up(incl, off);
    if (lane >= off) incl += u;
  }
  if (lane == 63) ws[wid] = incl;
  __syncthreads();
  int woff = bsum[blockIdx.x];
  for (int w = 0; w < wid; ++w) woff += ws[w];
  int excl = woff + incl - v;
  if (i < N) { row[i] = excl; cursor[i] = excl; }
}

// pos[e] = CSR slot of edge e (counting sort position among same-dst edges)
__global__ void k_pos(const int* __restrict__ dst, int* __restrict__ cursor,
                      int* __restrict__ pos, int E) {
  int e = blockIdx.x * blockDim.x + threadIdx.x;
  if (e < E) pos[e] = atomicAdd(&cursor[dst[e]], 1);
}

// hmid -> plain bf16; 2 edges/block, ea computed once in LDS
// [verified r18-r28: never appeared in top-5 counters; coalesced Ahi writes]
__global__ __launch_bounds__(256) void k_edge_mlp(
    const float* __restrict__ ea_in, const float* __restrict__ Wea,
    const float* __restrict__ bea, const float* __restrict__ We1,
    const float* __restrict__ be1, u16* __restrict__ Ahi, int E) {
  __shared__ float att[2][19];
  __shared__ float ea[2][12];
  int half = threadIdx.x >> 7;
  int t = threadIdx.x & 127;
  int e = blockIdx.x * 2 + half;
  bool real = (e < E);
  int ee = real ? e : E - 1;
  if (t < 19) att[half][t] = ea_in[(size_t)ee * 19 + t];
  __syncthreads();
  if (t < 12) {
    float a = bea[t];
#pragma unroll
    for (int k = 0; k < 19; ++k) a += att[half][k] * Wea[k * 12 + t];
    ea[half][t] = fmaxf(a, 0.0f);
  }
  __syncthreads();
  float a = be1[t];
#pragma unroll
  for (int j = 0; j < 12; ++j) a += ea[half][j] * We1[j * 128 + t];
  if (real) Ahi[(size_t)e * 128 + t] = f2bf(fmaxf(a, 0.0f));
}

// Fused prep: node MLP (h -> bf16) + W_e2 pack + GRU packs + W_l1 pack.
__global__ void k_prep_all(
    const float* __restrict__ x, const float* __restrict__ Wn,
    const float* __restrict__ bn, u16* __restrict__ hbf, int N, int nbNode,
    const float* __restrict__ W2, u16* __restrict__ Bph, int nbPack,
    const float* __restrict__ Wih, const float* __restrict__ Whh,
    u16* __restrict__ WpI, u16* __restrict__ WpH, int nbWtf,
    const float* __restrict__ Wl1, u16* __restrict__ Wp1) {
  int b = blockIdx.x;
  if (b < nbNode) {
    int tid = b * 256 + threadIdx.x;
    if (tid >= N * 64) return;
    int n = tid >> 6, f = tid & 63;
    float acc = bn[f];
    for (int k = 0; k < 8; ++k) acc += x[(size_t)n * 8 + k] * Wn[k * 64 + f];
    hbf[tid] = f2bf(fmaxf(acc, 0.0f));
  } else if (b < nbNode + nbPack) {
    int tid = (b - nbNode) * 256 + threadIdx.x;
    if (tid >= 128 * 4096) return;
    int j = tid & 7;
    int lane = (tid >> 3) & 63;
    int nt = (tid >> 9) & 3;
    int ks = (tid >> 11) & 3;
    int d = tid >> 13;
    int c = lane & 15, q = lane >> 4;
    int k = ks * 32 + q * 8 + j;
    int n = d * 64 + nt * 16 + c;
    Bph[tid] = f2bf(W2[(size_t)k * 4096 + n]);
  } else if (b < nbNode + nbPack + nbWtf) {
    int tid = (b - nbNode - nbPack) * 256 + threadIdx.x;
    if (tid >= 2 * 12288) return;
    int w = tid / 12288;
    int r = tid - w * 12288;
    int jj = r & 7;
    int lane = (r >> 3) & 63;
    int t = r >> 9;
    int nt = t % 12, ks = t / 12;
    int c = lane & 15, q = lane >> 4;
    int j = nt * 16 + c;
    int k = ks * 32 + q * 8 + jj;
    const float* W = w ? Whh : Wih;
    u16* Wp = w ? WpH : WpI;
    Wp[r] = f2bf(W[j * 64 + k]);
  } else {
    int tid = (b - nbNode - nbPack - nbWtf) * 256 + threadIdx.x;
    if (tid >= 3 * 8 * 64 * 8) return;
    int j = tid & 7;
    int lane = (tid >> 3) & 63;
    int nt = (tid >> 9) & 7;
    int ks = tid >> 12;
    int c = lane & 15, q = lane >> 4;
    int k = ks * 32 + q * 8 + j;
    int n = nt * 16 + c;
    Wp1[tid] = f2bf((k < 72) ? Wl1[k * 128 + n] : 0.0f);
  }
}

// Fused conv, r29 = r28 EXACTLY (verified best: 73.1us, 717 TF = 80% of the
// 2-barrier structure ceiling; 9 schedule/occupancy variants all neutral-to-
// worse -- structurally converged).
__global__ __launch_bounds__(256, 2) void k_conv_fused(
    const u16* __restrict__ Ahi, const u16* __restrict__ Bph,
    const float* __restrict__ b2, const u16* __restrict__ hbf,
    const int* __restrict__ src, const int* __restrict__ pos,
    u16* __restrict__ msgh, int E) {
  __shared__ __align__(16) u16 sB[2][8192];     // 2 x 16 KB B panels
  __shared__ __align__(16) float hsT[64 * 132]; // h[src[e], d] transposed: [d][edge]
  __shared__ __align__(16) u16 sb2h[4096];      // b2 as bf16
  int m0 = blockIdx.x * 128;
  int tid = threadIdx.x;
  int wave = tid >> 6, lane = tid & 63;
  int mw = wave >> 1, fw = wave & 1;
  int c = lane & 15, q = lane >> 4;

  auto stageB = [&](int d, int b) {
    const u16* gp = Bph + (size_t)d * 8192 + wave * 2048 + lane * 8;
    u16* lp = &sB[b][wave * 2048];
#pragma unroll
    for (int i = 0; i < 4; ++i)
      __builtin_amdgcn_global_load_lds(
          (const __attribute__((address_space(1))) unsigned int*)(gp + i * 512),
          (__attribute__((address_space(3))) unsigned int*)(lp + i * 512), 16, 0, 0);
  };

  stageB(0, 0);  // first panel in flight under the prologue

  // A fragments: 4 m-tiles x 4 k-slices, global->reg, held for whole kernel
  short8v afr[4][4];
#pragma unroll
  for (int mt = 0; mt < 4; ++mt) {
    int gr = m0 + mw * 64 + mt * 16 + c;
    if (gr >= E) gr = E - 1;
    const u16* ap = Ahi + (size_t)gr * 128 + q * 8;
#pragma unroll
    for (int ks = 0; ks < 4; ++ks) afr[mt][ks] = *(const short8v*)(ap + ks * 32);
  }

  // hsT: transposed stage of h[src[e], 0:64] (bf16 global -> f32 LDS)
#pragma unroll
  for (int p = 0; p < 8; ++p) {
    int slot = p * 256 + tid;
    int r = slot >> 4, s = slot & 15;  // edge r, d-quad s
    int ge = m0 + r;
    if (ge >= E) ge = E - 1;
    int sn = src[ge];
    ushort4 v = *(const ushort4*)(hbf + (size_t)sn * 64 + s * 4);
    hsT[(s * 4 + 0) * 132 + r] = bf2f(v.x);
    hsT[(s * 4 + 1) * 132 + r] = bf2f(v.y);
    hsT[(s * 4 + 2) * 132 + r] = bf2f(v.z);
    hsT[(s * 4 + 3) * 132 + r] = bf2f(v.w);
  }
  // sb2h: all 4096 b2 values as bf16
  {
    int t16 = tid * 16;
#pragma unroll
    for (int u = 0; u < 4; ++u) {
      float4 v = *(const float4*)(b2 + t16 + u * 4);
      sb2h[t16 + u * 4 + 0] = f2bf(v.x);
      sb2h[t16 + u * 4 + 1] = f2bf(v.y);
      sb2h[t16 + u * 4 + 2] = f2bf(v.z);
      sb2h[t16 + u * 4 + 3] = f2bf(v.w);
    }
  }
  __syncthreads();  // panel0 + hsT + sb2h ready

  float msg[4][2][4];
#pragma unroll
  for (int mt = 0; mt < 4; ++mt)
#pragma unroll
    for (int nt = 0; nt < 2; ++nt)
#pragma unroll
      for (int r = 0; r < 4; ++r) msg[mt][nt][r] = 0.0f;

  int cur = 0;
  for (int dl = 0; dl < 64; ++dl) {
    if (dl < 63) stageB(dl + 1, cur ^ 1);
    float b2v0 = bf2f(sb2h[dl * 64 + fw * 32 + c]);
    float b2v1 = bf2f(sb2h[dl * 64 + fw * 32 + 16 + c]);
    float4v acc[4][2];
#pragma unroll
    for (int mt = 0; mt < 4; ++mt)
#pragma unroll
      for (int nt = 0; nt < 2; ++nt) acc[mt][nt] = (float4v){0.f, 0.f, 0.f, 0.f};
    __builtin_amdgcn_s_setprio(1);
#pragma unroll
    for (int ks = 0; ks < 4; ++ks) {
      short8v b0 = *(const short8v*)(&sB[cur][ks * 2048 + fw * 1024 + lane * 8]);
      short8v b1 = *(const short8v*)(&sB[cur][ks * 2048 + fw * 1024 + 512 + lane * 8]);
#pragma unroll
      for (int mt = 0; mt < 4; ++mt) {
        acc[mt][0] = __builtin_amdgcn_mfma_f32_16x16x32_bf16(afr[mt][ks], b0, acc[mt][0], 0, 0, 0);
        acc[mt][1] = __builtin_amdgcn_mfma_f32_16x16x32_bf16(afr[mt][ks], b1, acc[mt][1], 0, 0, 0);
      }
    }
    __builtin_amdgcn_s_setprio(0);
#pragma unroll
    for (int mt = 0; mt < 4; ++mt) {
      float4 hd4 = *(const float4*)(&hsT[dl * 132 + mw * 64 + mt * 16 + q * 4]);
      float hd[4] = {hd4.x, hd4.y, hd4.z, hd4.w};
#pragma unroll
      for (int r = 0; r < 4; ++r) {
        msg[mt][0][r] += hd[r] * (acc[mt][0][r] + b2v0);
        msg[mt][1][r] += hd[r] * (acc[mt][1][r] + b2v1);
      }
    }
    __syncthreads();
    cur ^= 1;
  }

  // bf16 stores pre-permuted to CSR slot order: GRU reads contiguous rows
#pragma unroll
  for (int mt = 0; mt < 4; ++mt) {
#pragma unroll
    for (int r = 0; r < 4; ++r) {
      int e = m0 + mw * 64 + mt * 16 + q * 4 + r;
      if (e < E) {
        int pe = pos[e];
        u16* mp = msgh + (size_t)pe * 64 + fw * 32 + c;
        mp[0] = f2bf(msg[mt][0][r]);
        mp[16] = f2bf(msg[mt][1][r]);
      }
    }
  }
}

// MFMA GRU, r29: STREAM-THEN-REDUCE gather.
// A block's 64 nodes own a CONTIGUOUS msgh range [row[n0], row[n0+64])
// (avg 128 rows). Phase 1 streams it linearly into LDS (coalesced 16B loads,
// no divergence, no dependent chains -- replaces the latency-bound per-node
// global gather that ran at ~400 GB/s). Phase 2 reduces from LDS.
// Overflow beyond MCAP=256 rows (P ~ Poisson(128) tail, ~0) falls back to
// direct global reads -- correct for any degree distribution.
// LDS = 9216(sM)+9216(sH)+17408(sHf)+32768(sMsg)+260(sRow) ~= 68.9KB -> 2 blk/CU.
#define MCAP 256
__global__ __launch_bounds__(256, 2) void k_gru_mfma(
    const u16* __restrict__ msgh, const int* __restrict__ row,
    const float* __restrict__ cb, const u16* __restrict__ WpI,
    const u16* __restrict__ WpH, const float* __restrict__ bih,
    const float* __restrict__ bhh, const u16* __restrict__ hin,
    u16* __restrict__ hout, int N) {
  __shared__ __align__(16) u16 sM[64 * 72];
  __shared__ __align__(16) u16 sH[64 * 72];
  __shared__ __align__(16) float sHf[64 * 68];
  __shared__ __align__(16) u16 sMsg[MCAP * 64];
  __shared__ int sRow[65];
  int n0 = blockIdx.x * 64;
  int tid = threadIdx.x;
  if (tid < 65) {
    int idx = n0 + tid;
    sRow[tid] = row[(idx <= N) ? idx : N];
  }
  __syncthreads();
  int base = sRow[0];
  int S = sRow[64] - base;
  int Sc = (S < MCAP) ? S : MCAP;
  // phase 1: linear coalesced stream of msgh rows [base, base+Sc) into LDS
  {
    const u16* gp = msgh + (size_t)base * 64;
    int total8 = Sc * 8;  // 16B chunks
    for (int i = tid; i < total8; i += 256)
      *(short8v*)(&sMsg[i * 8]) = *(const short8v*)(gp + (size_t)i * 8);
  }
  __syncthreads();
  // phase 2: per-node reduction from LDS (global fallback past MCAP)
  {
    int nl = tid >> 4, fq = tid & 15;
    float4 cbv = *(const float4*)(cb + fq * 4);
#pragma unroll
    for (int pass = 0; pass < 4; ++pass) {
      int n = pass * 16 + nl;
      int gn = n0 + n;
      bool real = (gn < N);
      int b0 = sRow[n] - base, b1 = sRow[n + 1] - base;
      if (!real) b1 = b0;
      float4 av = {0.f, 0.f, 0.f, 0.f};
      for (int j = b0; j < b1; ++j) {
        ushort4 mv;
        if (j < MCAP) mv = *(const ushort4*)(&sMsg[j * 64 + fq * 4]);
        else mv = *(const ushort4*)(msgh + (size_t)(base + j) * 64 + fq * 4);
        av.x += bf2f(mv.x); av.y += bf2f(mv.y);
        av.z += bf2f(mv.z); av.w += bf2f(mv.w);
      }
      float cf = fmaxf((float)(b1 - b0), 1.0f);
      int hgn = real ? gn : N - 1;
      ushort4 hv = *(const ushort4*)(hin + (size_t)hgn * 64 + fq * 4);
      float hx = bf2f(hv.x), hy = bf2f(hv.y), hz = bf2f(hv.z), hw = bf2f(hv.w);
      float m0v = fmaxf(av.x / cf + cbv.x, 0.0f);
      float m1v = fmaxf(av.y / cf + cbv.y, 0.0f);
      float m2v = fmaxf(av.z / cf + cbv.z, 0.0f);
      float m3v = fmaxf(av.w / cf + cbv.w, 0.0f);
      ushort4 mu; mu.x = f2bf(m0v); mu.y = f2bf(m1v); mu.z = f2bf(m2v); mu.w = f2bf(m3v);
      *(ushort4*)(&sM[n * 72 + fq * 4]) = mu;
      *(ushort4*)(&sH[n * 72 + fq * 4]) = hv;  // already bf16
      float4 hf = {hx, hy, hz, hw};
      *(float4*)(&sHf[n * 68 + fq * 4]) = hf;
    }
  }
  __syncthreads();
  int wave = tid >> 6, lane = tid & 63;
  int c = lane & 15, q = lane >> 4;
  short8v am[2], ah[2];
#pragma unroll
  for (int ks = 0; ks < 2; ++ks) {
    am[ks] = *(const short8v*)(&sM[(wave * 16 + c) * 72 + ks * 32 + q * 8]);
    ah[ks] = *(const short8v*)(&sH[(wave * 16 + c) * 72 + ks * 32 + q * 8]);
  }
  float4v accRZ[8], accN[4], accHN[4];
#pragma unroll
  for (int i = 0; i < 8; ++i) accRZ[i] = (float4v){0.f, 0.f, 0.f, 0.f};
#pragma unroll
  for (int i = 0; i < 4; ++i) {
    accN[i] = (float4v){0.f, 0.f, 0.f, 0.f};
    accHN[i] = (float4v){0.f, 0.f, 0.f, 0.f};
  }
#pragma unroll
  for (int ks = 0; ks < 2; ++ks) {
#pragma unroll
    for (int nt = 0; nt < 8; ++nt) {
      short8v bI = *(const short8v*)(WpI + ((size_t)(ks * 12 + nt) * 64 + lane) * 8);
      short8v bH = *(const short8v*)(WpH + ((size_t)(ks * 12 + nt) * 64 + lane) * 8);
      accRZ[nt] = __builtin_amdgcn_mfma_f32_16x16x32_bf16(am[ks], bI, accRZ[nt], 0, 0, 0);
      accRZ[nt] = __builtin_amdgcn_mfma_f32_16x16x32_bf16(ah[ks], bH, accRZ[nt], 0, 0, 0);
    }
#pragma unroll
    for (int nt = 0; nt < 4; ++nt) {
      short8v bI = *(const short8v*)(WpI + ((size_t)(ks * 12 + 8 + nt) * 64 + lane) * 8);
      short8v bH = *(const short8v*)(WpH + ((size_t)(ks * 12 + 8 + nt) * 64 + lane) * 8);
      accN[nt] = __builtin_amdgcn_mfma_f32_16x16x32_bf16(am[ks], bI, accN[nt], 0, 0, 0);
      accHN[nt] = __builtin_amdgcn_mfma_f32_16x16x32_bf16(ah[ks], bH, accHN[nt], 0, 0, 0);
    }
  }
#pragma unroll
  for (int nt = 0; nt < 4; ++nt) {
    int f = nt * 16 + c;
    float brz_r = bih[f] + bhh[f];
    float brz_z = bih[64 + f] + bhh[64 + f];
    float bin = bih[128 + f];
    float bhn = bhh[128 + f];
#pragma unroll
    for (int r = 0; r < 4; ++r) {
      int nl = wave * 16 + q * 4 + r;
      int gn = n0 + nl;
      float rr = sigm(accRZ[nt][r] + brz_r);
      float zz = sigm(accRZ[nt + 4][r] + brz_z);
      float ng = tanhf(accN[nt][r] + bin + rr * (accHN[nt][r] + bhn));
      float hv = sHf[nl * 68 + f];
      if (gn < N) hout[(size_t)gn * 64 + f] = f2bf((1.0f - zz) * ng + zz * hv);
    }
  }
}

// MFMA final MLP, r28: bf16 h gather   [verified r28]
__global__ __launch_bounds__(256) void k_final_mfma(
    const u16* __restrict__ hbf, const float* __restrict__ ea3,
    const int* __restrict__ idx3, const u16* __restrict__ Wp1,
    const float* __restrict__ bl1, const float* __restrict__ Wl2,
    const float* __restrict__ bl2, float* __restrict__ out, int E3) {
  __shared__ __align__(16) u16 sF[64 * 104];
  int e0 = blockIdx.x * 64;
  int tid = threadIdx.x;
  {
    int er = tid >> 2;
    int part = tid & 3;
    int ge = e0 + er;
    int gc = (ge < E3) ? ge : E3 - 1;
    int a = idx3[gc], b = idx3[E3 + gc];
    const u16* pa = hbf + (size_t)a * 64 + part * 16;
    const u16* pb = hbf + (size_t)b * 64 + part * 16;
#pragma unroll
    for (int u = 0; u < 2; ++u) {
      short8v va = *(const short8v*)(pa + u * 8);
      short8v vb = *(const short8v*)(pb + u * 8);
      short8v mu;
#pragma unroll
      for (int i = 0; i < 8; ++i)
        mu[i] = (short)f2bf(0.5f * (bf2f((u16)va[i]) + bf2f((u16)vb[i])));
      *(short8v*)(&sF[er * 104 + part * 16 + u * 8]) = mu;
    }
    if (part == 0) {
      float4 e0v = *(const float4*)(ea3 + (size_t)gc * 8);
      float4 e1v = *(const float4*)(ea3 + (size_t)gc * 8 + 4);
      ushort4 u0, u1;
      u0.x = f2bf(e0v.x); u0.y = f2bf(e0v.y); u0.z = f2bf(e0v.z); u0.w = f2bf(e0v.w);
      u1.x = f2bf(e1v.x); u1.y = f2bf(e1v.y); u1.z = f2bf(e1v.z); u1.w = f2bf(e1v.w);
      *(ushort4*)(&sF[er * 104 + 64]) = u0;
      *(ushort4*)(&sF[er * 104 + 68]) = u1;
    } else {
      ushort4 z = {0, 0, 0, 0};
      *(ushort4*)(&sF[er * 104 + 72 + (part - 1) * 8]) = z;
      *(ushort4*)(&sF[er * 104 + 76 + (part - 1) * 8]) = z;
    }
  }
  __syncthreads();
  int wave = tid >> 6, lane = tid & 63;
  int c = lane & 15, q = lane >> 4;
  float4v acc[8];
#pragma unroll
  for (int nt = 0; nt < 8; ++nt) acc[nt] = (float4v){0.f, 0.f, 0.f, 0.f};
#pragma unroll
  for (int ks = 0; ks < 3; ++ks) {
    short8v af = *(const short8v*)(&sF[(wave * 16 + c) * 104 + ks * 32 + q * 8]);
#pragma unroll
    for (int nt = 0; nt < 8; ++nt) {
      short8v bf = *(const short8v*)(Wp1 + ((size_t)(ks * 8 + nt) * 64 + lane) * 8);
      acc[nt] = __builtin_amdgcn_mfma_f32_16x16x32_bf16(af, bf, acc[nt], 0, 0, 0);
    }
  }
  float v[4] = {0.f, 0.f, 0.f, 0.f};
#pragma unroll
  for (int nt = 0; nt < 8; ++nt) {
    int n = nt * 16 + c;
    float b1 = bl1[n];
    float w2 = Wl2[n];
#pragma unroll
    for (int r = 0; r < 4; ++r) v[r] += fmaxf(acc[nt][r] + b1, 0.0f) * w2;
  }
#pragma unroll
  for (int off = 1; off < 16; off <<= 1) {
#pragma unroll
    for (int r = 0; r < 4; ++r) v[r] += __shfl_xor(v[r], off);
  }
  if (c == 0) {
    float b2v = bl2[0];
#pragma unroll
    for (int r = 0; r < 4; ++r) {
      int e = e0 + wave * 16 + q * 4 + r;
      if (e < E3) out[e] = v[r] + b2v;
    }
  }
}

extern "C" void kernel_launch(void* const* d_in, const int* in_sizes, int n_in,
                              void* d_out, int out_size, void* d_ws, size_t ws_size,
                              hipStream_t stream) {
  const float* x          = (const float*)d_in[0];
  const float* edge_attr  = (const float*)d_in[1];
  const float* edge_attr3 = (const float*)d_in[2];
  const int*   edge_index = (const int*)d_in[3];
  const int*   edge_index3= (const int*)d_in[4];
  const float* W_node = (const float*)d_in[5];
  const float* b_node = (const float*)d_in[6];
  const float* W_ea   = (const float*)d_in[7];
  const float* b_ea   = (const float*)d_in[8];
  const float* W_e1   = (const float*)d_in[9];
  const float* b_e1   = (const float*)d_in[10];
  const float* W_e2   = (const float*)d_in[11];
  const float* b_e2   = (const float*)d_in[12];
  const float* conv_bias = (const float*)d_in[13];
  const float* W_ih   = (const float*)d_in[14];
  const float* b_ih   = (const float*)d_in[15];
  const float* W_hh   = (const float*)d_in[16];
  const float* b_hh   = (const float*)d_in[17];
  const float* W_l1   = (const float*)d_in[18];
  const float* b_l1   = (const float*)d_in[19];
  const float* W_l2   = (const float*)d_in[20];
  const float* b_l2   = (const float*)d_in[21];

  int N  = in_sizes[0] / 8;
  int E  = in_sizes[1] / 19;
  int E3 = in_sizes[2] / 8;

  char* p = (char*)d_ws;
  auto carve = [&](size_t bytes) -> void* {
    char* q = p;
    p += (bytes + 255) & ~(size_t)255;
    return (void*)q;
  };
  u16*   hA    = (u16*)carve((size_t)N * 64 * 2);
  u16*   hB    = (u16*)carve((size_t)N * 64 * 2);
  u16*   msgh  = (u16*)carve((size_t)E * 64 * 2);
  int*   cnt   = (int*)carve((size_t)N * 4);
  int*   row   = (int*)carve((size_t)(N + 1) * 4);
  int*   cursor= (int*)carve((size_t)N * 4);
  int*   pos   = (int*)carve((size_t)E * 4);
  int*   bsum  = (int*)carve(256 * 4);
  u16*   Ahi   = (u16*)carve((size_t)E * 128 * 2);
  u16*   Bph   = (u16*)carve((size_t)128 * 4096 * 2);
  u16*   WpI   = (u16*)carve(12288 * 2);
  u16*   WpH   = (u16*)carve(12288 * 2);
  u16*   Wp1   = (u16*)carve(12288 * 2);

  const int* src = edge_index;
  const int* dst = edge_index + E;

  int nb = (N + 255) / 256;
  // CSR build (once)
  hipMemsetAsync(cnt, 0, (size_t)N * 4, stream);
  k_cnt<<<(E + 255) / 256, 256, 0, stream>>>(dst, cnt, E);
  k_scan1<<<nb, 256, 0, stream>>>(cnt, bsum, N);
  k_scan2<<<1, 256, 0, stream>>>(bsum, row, nb, N);
  k_scan3<<<nb, 256, 0, stream>>>(cnt, bsum, row, cursor, N);
  k_pos<<<(E + 255) / 256, 256, 0, stream>>>(dst, cursor, pos, E);

  k_edge_mlp<<<(E + 1) / 2, 256, 0, stream>>>(edge_attr, W_ea, b_ea, W_e1, b_e1, Ahi, E);
  int nbNode = ((size_t)N * 64 + 255) / 256;
  int nbPack = (128 * 4096 + 255) / 256;
  int nbWtf  = (2 * 12288 + 255) / 256;
  int nbWl1  = (12288 + 255) / 256;
  k_prep_all<<<nbNode + nbPack + nbWtf + nbWl1, 256, 0, stream>>>(
      x, W_node, b_node, hA, N, nbNode, W_e2, Bph, nbPack,
      W_ih, W_hh, WpI, WpH, nbWtf, W_l1, Wp1);

  u16* hcur = hA;
  u16* hnxt = hB;
  int gconv = (E + 127) / 128;
  int ngru = (N + 63) / 64;
  for (int it = 0; it < 3; ++it) {
    k_conv_fused<<<gconv, 256, 0, stream>>>(Ahi, Bph, b_e2, hcur, src, pos, msgh, E);
    k_gru_mfma<<<ngru, 256, 0, stream>>>(msgh, row, conv_bias, WpI, WpH,
                                         b_ih, b_hh, hcur, hnxt, N);
    u16* tmp = hcur; hcur = hnxt; hnxt = tmp;
  }
  k_final_mfma<<<(E3 + 63) / 64, 256, 0, stream>>>(hcur, edge_attr3, edge_index3, Wp1,
                                                   b_l1, W_l2, b_l2, (float*)d_out, E3);
}

// Round 12
// 386.245 us; speedup vs baseline: 1.3156x; 1.0049x over previous
//
#include <hip/hip_runtime.h>

typedef unsigned short u16;
typedef unsigned int u32;
typedef __attribute__((ext_vector_type(8))) short short8v;
typedef __attribute__((ext_vector_type(4))) float float4v;

__device__ __forceinline__ float sigm(float x) { return 1.0f / (1.0f + __expf(-x)); }
__device__ __forceinline__ u16 f2bf(float f) {
  u32 u = __float_as_uint(f);
  u32 r = (u + 0x7fffu + ((u >> 16) & 1u)) >> 16;
  return (u16)r;
}
__device__ __forceinline__ float bf2f(u16 w) { return __uint_as_float(((u32)w) << 16); }

__global__ void k_cnt(const int* __restrict__ dst, int* __restrict__ cnt, int E) {
  int e = blockIdx.x * blockDim.x + threadIdx.x;
  if (e < E) atomicAdd(&cnt[dst[e]], 1);
}

// --- parallel scan: scan1 block sums -> scan2 scan of ~98 sums -> scan3 local scan ---
__global__ void k_scan1(const int* __restrict__ cnt, int* __restrict__ bsum, int N) {
  __shared__ int ws[4];
  int t = threadIdx.x;
  int i = blockIdx.x * 256 + t;
  int v = (i < N) ? cnt[i] : 0;
  int s = v;
  for (int off = 1; off < 64; off <<= 1) s += __shfl_xor(s, off);
  int wid = t >> 6, lane = t & 63;
  if (lane == 0) ws[wid] = s;
  __syncthreads();
  if (t == 0) bsum[blockIdx.x] = ws[0] + ws[1] + ws[2] + ws[3];
}

__global__ void k_scan2(int* __restrict__ bsum, int* __restrict__ row, int nb, int N) {
  __shared__ int s[256];
  int t = threadIdx.x;
  if (t < nb) s[t] = bsum[t];
  __syncthreads();
  if (t == 0) {
    int run = 0;
    for (int i = 0; i < nb; ++i) { int x = s[i]; s[i] = run; run += x; }
    row[N] = run;
  }
  __syncthreads();
  if (t < nb) bsum[t] = s[t];
}

__global__ void k_scan3(const int* __restrict__ cnt, const int* __restrict__ bsum,
                        int* __restrict__ row, int* __restrict__ cursor, int N) {
  __shared__ int ws[4];
  int t = threadIdx.x;
  int i = blockIdx.x * 256 + t;
  int v = (i < N) ? cnt[i] : 0;
  int lane = t & 63, wid = t >> 6;
  int incl = v;
  for (int off = 1; off < 64; off <<= 1) {
    int u = __shfl_up(incl, off);
    if (lane >= off) incl += u;
  }
  if (lane == 63) ws[wid] = incl;
  __syncthreads();
  int woff = bsum[blockIdx.x];
  for (int w = 0; w < wid; ++w) woff += ws[w];
  int excl = woff + incl - v;
  if (i < N) { row[i] = excl; cursor[i] = excl; }
}

// pos[e] = CSR slot of edge e (counting sort position among same-dst edges)
__global__ void k_pos(const int* __restrict__ dst, int* __restrict__ cursor,
                      int* __restrict__ pos, int E) {
  int e = blockIdx.x * blockDim.x + threadIdx.x;
  if (e < E) pos[e] = atomicAdd(&cursor[dst[e]], 1);
}

// hmid -> plain bf16; 2 edges/block, ea computed once in LDS
// [verified r18-r29: never appeared in top-5 counters; coalesced Ahi writes]
__global__ __launch_bounds__(256) void k_edge_mlp(
    const float* __restrict__ ea_in, const float* __restrict__ Wea,
    const float* __restrict__ bea, const float* __restrict__ We1,
    const float* __restrict__ be1, u16* __restrict__ Ahi, int E) {
  __shared__ float att[2][19];
  __shared__ float ea[2][12];
  int half = threadIdx.x >> 7;
  int t = threadIdx.x & 127;
  int e = blockIdx.x * 2 + half;
  bool real = (e < E);
  int ee = real ? e : E - 1;
  if (t < 19) att[half][t] = ea_in[(size_t)ee * 19 + t];
  __syncthreads();
  if (t < 12) {
    float a = bea[t];
#pragma unroll
    for (int k = 0; k < 19; ++k) a += att[half][k] * Wea[k * 12 + t];
    ea[half][t] = fmaxf(a, 0.0f);
  }
  __syncthreads();
  float a = be1[t];
#pragma unroll
  for (int j = 0; j < 12; ++j) a += ea[half][j] * We1[j * 128 + t];
  if (real) Ahi[(size_t)e * 128 + t] = f2bf(fmaxf(a, 0.0f));
}

// Fused prep: node MLP (h -> bf16) + W_e2 pack + GRU packs + W_l1 pack.
__global__ void k_prep_all(
    const float* __restrict__ x, const float* __restrict__ Wn,
    const float* __restrict__ bn, u16* __restrict__ hbf, int N, int nbNode,
    const float* __restrict__ W2, u16* __restrict__ Bph, int nbPack,
    const float* __restrict__ Wih, const float* __restrict__ Whh,
    u16* __restrict__ WpI, u16* __restrict__ WpH, int nbWtf,
    const float* __restrict__ Wl1, u16* __restrict__ Wp1) {
  int b = blockIdx.x;
  if (b < nbNode) {
    int tid = b * 256 + threadIdx.x;
    if (tid >= N * 64) return;
    int n = tid >> 6, f = tid & 63;
    float acc = bn[f];
    for (int k = 0; k < 8; ++k) acc += x[(size_t)n * 8 + k] * Wn[k * 64 + f];
    hbf[tid] = f2bf(fmaxf(acc, 0.0f));
  } else if (b < nbNode + nbPack) {
    int tid = (b - nbNode) * 256 + threadIdx.x;
    if (tid >= 128 * 4096) return;
    int j = tid & 7;
    int lane = (tid >> 3) & 63;
    int nt = (tid >> 9) & 3;
    int ks = (tid >> 11) & 3;
    int d = tid >> 13;
    int c = lane & 15, q = lane >> 4;
    int k = ks * 32 + q * 8 + j;
    int n = d * 64 + nt * 16 + c;
    Bph[tid] = f2bf(W2[(size_t)k * 4096 + n]);
  } else if (b < nbNode + nbPack + nbWtf) {
    int tid = (b - nbNode - nbPack) * 256 + threadIdx.x;
    if (tid >= 2 * 12288) return;
    int w = tid / 12288;
    int r = tid - w * 12288;
    int jj = r & 7;
    int lane = (r >> 3) & 63;
    int t = r >> 9;
    int nt = t % 12, ks = t / 12;
    int c = lane & 15, q = lane >> 4;
    int j = nt * 16 + c;
    int k = ks * 32 + q * 8 + jj;
    const float* W = w ? Whh : Wih;
    u16* Wp = w ? WpH : WpI;
    Wp[r] = f2bf(W[j * 64 + k]);
  } else {
    int tid = (b - nbNode - nbPack - nbWtf) * 256 + threadIdx.x;
    if (tid >= 3 * 8 * 64 * 8) return;
    int j = tid & 7;
    int lane = (tid >> 3) & 63;
    int nt = (tid >> 9) & 7;
    int ks = tid >> 12;
    int c = lane & 15, q = lane >> 4;
    int k = ks * 32 + q * 8 + j;
    int n = nt * 16 + c;
    Wp1[tid] = f2bf((k < 72) ? Wl1[k * 128 + n] : 0.0f);
  }
}

// Fused conv = r28/r29 EXACTLY (verified best: 73.0us, 717 TF = 80% of the
// 2-barrier structure ceiling; 9 schedule/occupancy variants all neutral-to-
// worse -- structurally converged).
__global__ __launch_bounds__(256, 2) void k_conv_fused(
    const u16* __restrict__ Ahi, const u16* __restrict__ Bph,
    const float* __restrict__ b2, const u16* __restrict__ hbf,
    const int* __restrict__ src, const int* __restrict__ pos,
    u16* __restrict__ msgh, int E) {
  __shared__ __align__(16) u16 sB[2][8192];     // 2 x 16 KB B panels
  __shared__ __align__(16) float hsT[64 * 132]; // h[src[e], d] transposed: [d][edge]
  __shared__ __align__(16) u16 sb2h[4096];      // b2 as bf16
  int m0 = blockIdx.x * 128;
  int tid = threadIdx.x;
  int wave = tid >> 6, lane = tid & 63;
  int mw = wave >> 1, fw = wave & 1;
  int c = lane & 15, q = lane >> 4;

  auto stageB = [&](int d, int b) {
    const u16* gp = Bph + (size_t)d * 8192 + wave * 2048 + lane * 8;
    u16* lp = &sB[b][wave * 2048];
#pragma unroll
    for (int i = 0; i < 4; ++i)
      __builtin_amdgcn_global_load_lds(
          (const __attribute__((address_space(1))) unsigned int*)(gp + i * 512),
          (__attribute__((address_space(3))) unsigned int*)(lp + i * 512), 16, 0, 0);
  };

  stageB(0, 0);  // first panel in flight under the prologue

  // A fragments: 4 m-tiles x 4 k-slices, global->reg, held for whole kernel
  short8v afr[4][4];
#pragma unroll
  for (int mt = 0; mt < 4; ++mt) {
    int gr = m0 + mw * 64 + mt * 16 + c;
    if (gr >= E) gr = E - 1;
    const u16* ap = Ahi + (size_t)gr * 128 + q * 8;
#pragma unroll
    for (int ks = 0; ks < 4; ++ks) afr[mt][ks] = *(const short8v*)(ap + ks * 32);
  }

  // hsT: transposed stage of h[src[e], 0:64] (bf16 global -> f32 LDS)
#pragma unroll
  for (int p = 0; p < 8; ++p) {
    int slot = p * 256 + tid;
    int r = slot >> 4, s = slot & 15;  // edge r, d-quad s
    int ge = m0 + r;
    if (ge >= E) ge = E - 1;
    int sn = src[ge];
    ushort4 v = *(const ushort4*)(hbf + (size_t)sn * 64 + s * 4);
    hsT[(s * 4 + 0) * 132 + r] = bf2f(v.x);
    hsT[(s * 4 + 1) * 132 + r] = bf2f(v.y);
    hsT[(s * 4 + 2) * 132 + r] = bf2f(v.z);
    hsT[(s * 4 + 3) * 132 + r] = bf2f(v.w);
  }
  // sb2h: all 4096 b2 values as bf16
  {
    int t16 = tid * 16;
#pragma unroll
    for (int u = 0; u < 4; ++u) {
      float4 v = *(const float4*)(b2 + t16 + u * 4);
      sb2h[t16 + u * 4 + 0] = f2bf(v.x);
      sb2h[t16 + u * 4 + 1] = f2bf(v.y);
      sb2h[t16 + u * 4 + 2] = f2bf(v.z);
      sb2h[t16 + u * 4 + 3] = f2bf(v.w);
    }
  }
  __syncthreads();  // panel0 + hsT + sb2h ready

  float msg[4][2][4];
#pragma unroll
  for (int mt = 0; mt < 4; ++mt)
#pragma unroll
    for (int nt = 0; nt < 2; ++nt)
#pragma unroll
      for (int r = 0; r < 4; ++r) msg[mt][nt][r] = 0.0f;

  int cur = 0;
  for (int dl = 0; dl < 64; ++dl) {
    if (dl < 63) stageB(dl + 1, cur ^ 1);
    float b2v0 = bf2f(sb2h[dl * 64 + fw * 32 + c]);
    float b2v1 = bf2f(sb2h[dl * 64 + fw * 32 + 16 + c]);
    float4v acc[4][2];
#pragma unroll
    for (int mt = 0; mt < 4; ++mt)
#pragma unroll
      for (int nt = 0; nt < 2; ++nt) acc[mt][nt] = (float4v){0.f, 0.f, 0.f, 0.f};
    __builtin_amdgcn_s_setprio(1);
#pragma unroll
    for (int ks = 0; ks < 4; ++ks) {
      short8v b0 = *(const short8v*)(&sB[cur][ks * 2048 + fw * 1024 + lane * 8]);
      short8v b1 = *(const short8v*)(&sB[cur][ks * 2048 + fw * 1024 + 512 + lane * 8]);
#pragma unroll
      for (int mt = 0; mt < 4; ++mt) {
        acc[mt][0] = __builtin_amdgcn_mfma_f32_16x16x32_bf16(afr[mt][ks], b0, acc[mt][0], 0, 0, 0);
        acc[mt][1] = __builtin_amdgcn_mfma_f32_16x16x32_bf16(afr[mt][ks], b1, acc[mt][1], 0, 0, 0);
      }
    }
    __builtin_amdgcn_s_setprio(0);
#pragma unroll
    for (int mt = 0; mt < 4; ++mt) {
      float4 hd4 = *(const float4*)(&hsT[dl * 132 + mw * 64 + mt * 16 + q * 4]);
      float hd[4] = {hd4.x, hd4.y, hd4.z, hd4.w};
#pragma unroll
      for (int r = 0; r < 4; ++r) {
        msg[mt][0][r] += hd[r] * (acc[mt][0][r] + b2v0);
        msg[mt][1][r] += hd[r] * (acc[mt][1][r] + b2v1);
      }
    }
    __syncthreads();
    cur ^= 1;
  }

  // bf16 stores pre-permuted to CSR slot order: GRU reads contiguous rows
#pragma unroll
  for (int mt = 0; mt < 4; ++mt) {
#pragma unroll
    for (int r = 0; r < 4; ++r) {
      int e = m0 + mw * 64 + mt * 16 + q * 4 + r;
      if (e < E) {
        int pe = pos[e];
        u16* mp = msgh + (size_t)pe * 64 + fw * 32 + c;
        mp[0] = f2bf(msg[mt][0][r]);
        mp[16] = f2bf(msg[mt][1][r]);
      }
    }
  }
}

// MFMA GRU, r30: r29 stream-then-reduce + sHf REMOVED (bitwise-redundant:
// hin is bf16, so sHf[n][f] == bf2f(sH[n][f]) exactly -- epilogue reads sH).
// LDS 68.9 -> 51.5 KB -> 3 blocks/CU (was 2): stream/reduce/MFMA phases of
// three co-resident blocks overlap.
#define MCAP 256
__global__ __launch_bounds__(256, 3) void k_gru_mfma(
    const u16* __restrict__ msgh, const int* __restrict__ row,
    const float* __restrict__ cb, const u16* __restrict__ WpI,
    const u16* __restrict__ WpH, const float* __restrict__ bih,
    const float* __restrict__ bhh, const u16* __restrict__ hin,
    u16* __restrict__ hout, int N) {
  __shared__ __align__(16) u16 sM[64 * 72];
  __shared__ __align__(16) u16 sH[64 * 72];
  __shared__ __align__(16) u16 sMsg[MCAP * 64];
  __shared__ int sRow[65];
  int n0 = blockIdx.x * 64;
  int tid = threadIdx.x;
  if (tid < 65) {
    int idx = n0 + tid;
    sRow[tid] = row[(idx <= N) ? idx : N];
  }
  __syncthreads();
  int base = sRow[0];
  int S = sRow[64] - base;
  int Sc = (S < MCAP) ? S : MCAP;
  // phase 1: linear coalesced stream of msgh rows [base, base+Sc) into LDS
  {
    const u16* gp = msgh + (size_t)base * 64;
    int total8 = Sc * 8;  // 16B chunks
    for (int i = tid; i < total8; i += 256)
      *(short8v*)(&sMsg[i * 8]) = *(const short8v*)(gp + (size_t)i * 8);
  }
  __syncthreads();
  // phase 2: per-node reduction from LDS (global fallback past MCAP)
  {
    int nl = tid >> 4, fq = tid & 15;
    float4 cbv = *(const float4*)(cb + fq * 4);
#pragma unroll
    for (int pass = 0; pass < 4; ++pass) {
      int n = pass * 16 + nl;
      int gn = n0 + n;
      bool real = (gn < N);
      int b0 = sRow[n] - base, b1 = sRow[n + 1] - base;
      if (!real) b1 = b0;
      float4 av = {0.f, 0.f, 0.f, 0.f};
      for (int j = b0; j < b1; ++j) {
        ushort4 mv;
        if (j < MCAP) mv = *(const ushort4*)(&sMsg[j * 64 + fq * 4]);
        else mv = *(const ushort4*)(msgh + (size_t)(base + j) * 64 + fq * 4);
        av.x += bf2f(mv.x); av.y += bf2f(mv.y);
        av.z += bf2f(mv.z); av.w += bf2f(mv.w);
      }
      float cf = fmaxf((float)(b1 - b0), 1.0f);
      int hgn = real ? gn : N - 1;
      ushort4 hv = *(const ushort4*)(hin + (size_t)hgn * 64 + fq * 4);
      float m0v = fmaxf(av.x / cf + cbv.x, 0.0f);
      float m1v = fmaxf(av.y / cf + cbv.y, 0.0f);
      float m2v = fmaxf(av.z / cf + cbv.z, 0.0f);
      float m3v = fmaxf(av.w / cf + cbv.w, 0.0f);
      ushort4 mu; mu.x = f2bf(m0v); mu.y = f2bf(m1v); mu.z = f2bf(m2v); mu.w = f2bf(m3v);
      *(ushort4*)(&sM[n * 72 + fq * 4]) = mu;
      *(ushort4*)(&sH[n * 72 + fq * 4]) = hv;  // already bf16
    }
  }
  __syncthreads();
  int wave = tid >> 6, lane = tid & 63;
  int c = lane & 15, q = lane >> 4;
  short8v am[2], ah[2];
#pragma unroll
  for (int ks = 0; ks < 2; ++ks) {
    am[ks] = *(const short8v*)(&sM[(wave * 16 + c) * 72 + ks * 32 + q * 8]);
    ah[ks] = *(const short8v*)(&sH[(wave * 16 + c) * 72 + ks * 32 + q * 8]);
  }
  float4v accRZ[8], accN[4], accHN[4];
#pragma unroll
  for (int i = 0; i < 8; ++i) accRZ[i] = (float4v){0.f, 0.f, 0.f, 0.f};
#pragma unroll
  for (int i = 0; i < 4; ++i) {
    accN[i] = (float4v){0.f, 0.f, 0.f, 0.f};
    accHN[i] = (float4v){0.f, 0.f, 0.f, 0.f};
  }
#pragma unroll
  for (int ks = 0; ks < 2; ++ks) {
#pragma unroll
    for (int nt = 0; nt < 8; ++nt) {
      short8v bI = *(const short8v*)(WpI + ((size_t)(ks * 12 + nt) * 64 + lane) * 8);
      short8v bH = *(const short8v*)(WpH + ((size_t)(ks * 12 + nt) * 64 + lane) * 8);
      accRZ[nt] = __builtin_amdgcn_mfma_f32_16x16x32_bf16(am[ks], bI, accRZ[nt], 0, 0, 0);
      accRZ[nt] = __builtin_amdgcn_mfma_f32_16x16x32_bf16(ah[ks], bH, accRZ[nt], 0, 0, 0);
    }
#pragma unroll
    for (int nt = 0; nt < 4; ++nt) {
      short8v bI = *(const short8v*)(WpI + ((size_t)(ks * 12 + 8 + nt) * 64 + lane) * 8);
      short8v bH = *(const short8v*)(WpH + ((size_t)(ks * 12 + 8 + nt) * 64 + lane) * 8);
      accN[nt] = __builtin_amdgcn_mfma_f32_16x16x32_bf16(am[ks], bI, accN[nt], 0, 0, 0);
      accHN[nt] = __builtin_amdgcn_mfma_f32_16x16x32_bf16(ah[ks], bH, accHN[nt], 0, 0, 0);
    }
  }
#pragma unroll
  for (int nt = 0; nt < 4; ++nt) {
    int f = nt * 16 + c;
    float brz_r = bih[f] + bhh[f];
    float brz_z = bih[64 + f] + bhh[64 + f];
    float bin = bih[128 + f];
    float bhn = bhh[128 + f];
#pragma unroll
    for (int r = 0; r < 4; ++r) {
      int nl = wave * 16 + q * 4 + r;
      int gn = n0 + nl;
      float rr = sigm(accRZ[nt][r] + brz_r);
      float zz = sigm(accRZ[nt + 4][r] + brz_z);
      float ng = tanhf(accN[nt][r] + bin + rr * (accHN[nt][r] + bhn));
      float hv = bf2f(sH[nl * 72 + f]);  // == old sHf value exactly
      if (gn < N) hout[(size_t)gn * 64 + f] = f2bf((1.0f - zz) * ng + zz * hv);
    }
  }
}

// MFMA final MLP, r28: bf16 h gather   [verified r28/r29]
__global__ __launch_bounds__(256) void k_final_mfma(
    const u16* __restrict__ hbf, const float* __restrict__ ea3,
    const int* __restrict__ idx3, const u16* __restrict__ Wp1,
    const float* __restrict__ bl1, const float* __restrict__ Wl2,
    const float* __restrict__ bl2, float* __restrict__ out, int E3) {
  __shared__ __align__(16) u16 sF[64 * 104];
  int e0 = blockIdx.x * 64;
  int tid = threadIdx.x;
  {
    int er = tid >> 2;
    int part = tid & 3;
    int ge = e0 + er;
    int gc = (ge < E3) ? ge : E3 - 1;
    int a = idx3[gc], b = idx3[E3 + gc];
    const u16* pa = hbf + (size_t)a * 64 + part * 16;
    const u16* pb = hbf + (size_t)b * 64 + part * 16;
#pragma unroll
    for (int u = 0; u < 2; ++u) {
      short8v va = *(const short8v*)(pa + u * 8);
      short8v vb = *(const short8v*)(pb + u * 8);
      short8v mu;
#pragma unroll
      for (int i = 0; i < 8; ++i)
        mu[i] = (short)f2bf(0.5f * (bf2f((u16)va[i]) + bf2f((u16)vb[i])));
      *(short8v*)(&sF[er * 104 + part * 16 + u * 8]) = mu;
    }
    if (part == 0) {
      float4 e0v = *(const float4*)(ea3 + (size_t)gc * 8);
      float4 e1v = *(const float4*)(ea3 + (size_t)gc * 8 + 4);
      ushort4 u0, u1;
      u0.x = f2bf(e0v.x); u0.y = f2bf(e0v.y); u0.z = f2bf(e0v.z); u0.w = f2bf(e0v.w);
      u1.x = f2bf(e1v.x); u1.y = f2bf(e1v.y); u1.z = f2bf(e1v.z); u1.w = f2bf(e1v.w);
      *(ushort4*)(&sF[er * 104 + 64]) = u0;
      *(ushort4*)(&sF[er * 104 + 68]) = u1;
    } else {
      ushort4 z = {0, 0, 0, 0};
      *(ushort4*)(&sF[er * 104 + 72 + (part - 1) * 8]) = z;
      *(ushort4*)(&sF[er * 104 + 76 + (part - 1) * 8]) = z;
    }
  }
  __syncthreads();
  int wave = tid >> 6, lane = tid & 63;
  int c = lane & 15, q = lane >> 4;
  float4v acc[8];
#pragma unroll
  for (int nt = 0; nt < 8; ++nt) acc[nt] = (float4v){0.f, 0.f, 0.f, 0.f};
#pragma unroll
  for (int ks = 0; ks < 3; ++ks) {
    short8v af = *(const short8v*)(&sF[(wave * 16 + c) * 104 + ks * 32 + q * 8]);
#pragma unroll
    for (int nt = 0; nt < 8; ++nt) {
      short8v bf = *(const short8v*)(Wp1 + ((size_t)(ks * 8 + nt) * 64 + lane) * 8);
      acc[nt] = __builtin_amdgcn_mfma_f32_16x16x32_bf16(af, bf, acc[nt], 0, 0, 0);
    }
  }
  float v[4] = {0.f, 0.f, 0.f, 0.f};
#pragma unroll
  for (int nt = 0; nt < 8; ++nt) {
    int n = nt * 16 + c;
    float b1 = bl1[n];
    float w2 = Wl2[n];
#pragma unroll
    for (int r = 0; r < 4; ++r) v[r] += fmaxf(acc[nt][r] + b1, 0.0f) * w2;
  }
#pragma unroll
  for (int off = 1; off < 16; off <<= 1) {
#pragma unroll
    for (int r = 0; r < 4; ++r) v[r] += __shfl_xor(v[r], off);
  }
  if (c == 0) {
    float b2v = bl2[0];
#pragma unroll
    for (int r = 0; r < 4; ++r) {
      int e = e0 + wave * 16 + q * 4 + r;
      if (e < E3) out[e] = v[r] + b2v;
    }
  }
}

extern "C" void kernel_launch(void* const* d_in, const int* in_sizes, int n_in,
                              void* d_out, int out_size, void* d_ws, size_t ws_size,
                              hipStream_t stream) {
  const float* x          = (const float*)d_in[0];
  const float* edge_attr  = (const float*)d_in[1];
  const float* edge_attr3 = (const float*)d_in[2];
  const int*   edge_index = (const int*)d_in[3];
  const int*   edge_index3= (const int*)d_in[4];
  const float* W_node = (const float*)d_in[5];
  const float* b_node = (const float*)d_in[6];
  const float* W_ea   = (const float*)d_in[7];
  const float* b_ea   = (const float*)d_in[8];
  const float* W_e1   = (const float*)d_in[9];
  const float* b_e1   = (const float*)d_in[10];
  const float* W_e2   = (const float*)d_in[11];
  const float* b_e2   = (const float*)d_in[12];
  const float* conv_bias = (const float*)d_in[13];
  const float* W_ih   = (const float*)d_in[14];
  const float* b_ih   = (const float*)d_in[15];
  const float* W_hh   = (const float*)d_in[16];
  const float* b_hh   = (const float*)d_in[17];
  const float* W_l1   = (const float*)d_in[18];
  const float* b_l1   = (const float*)d_in[19];
  const float* W_l2   = (const float*)d_in[20];
  const float* b_l2   = (const float*)d_in[21];

  int N  = in_sizes[0] / 8;
  int E  = in_sizes[1] / 19;
  int E3 = in_sizes[2] / 8;

  char* p = (char*)d_ws;
  auto carve = [&](size_t bytes) -> void* {
    char* q = p;
    p += (bytes + 255) & ~(size_t)255;
    return (void*)q;
  };
  u16*   hA    = (u16*)carve((size_t)N * 64 * 2);
  u16*   hB    = (u16*)carve((size_t)N * 64 * 2);
  u16*   msgh  = (u16*)carve((size_t)E * 64 * 2);
  int*   cnt   = (int*)carve((size_t)N * 4);
  int*   row   = (int*)carve((size_t)(N + 1) * 4);
  int*   cursor= (int*)carve((size_t)N * 4);
  int*   pos   = (int*)carve((size_t)E * 4);
  int*   bsum  = (int*)carve(256 * 4);
  u16*   Ahi   = (u16*)carve((size_t)E * 128 * 2);
  u16*   Bph   = (u16*)carve((size_t)128 * 4096 * 2);
  u16*   WpI   = (u16*)carve(12288 * 2);
  u16*   WpH   = (u16*)carve(12288 * 2);
  u16*   Wp1   = (u16*)carve(12288 * 2);

  const int* src = edge_index;
  const int* dst = edge_index + E;

  int nb = (N + 255) / 256;
  // CSR build (once)
  hipMemsetAsync(cnt, 0, (size_t)N * 4, stream);
  k_cnt<<<(E + 255) / 256, 256, 0, stream>>>(dst, cnt, E);
  k_scan1<<<nb, 256, 0, stream>>>(cnt, bsum, N);
  k_scan2<<<1, 256, 0, stream>>>(bsum, row, nb, N);
  k_scan3<<<nb, 256, 0, stream>>>(cnt, bsum, row, cursor, N);
  k_pos<<<(E + 255) / 256, 256, 0, stream>>>(dst, cursor, pos, E);

  k_edge_mlp<<<(E + 1) / 2, 256, 0, stream>>>(edge_attr, W_ea, b_ea, W_e1, b_e1, Ahi, E);
  int nbNode = ((size_t)N * 64 + 255) / 256;
  int nbPack = (128 * 4096 + 255) / 256;
  int nbWtf  = (2 * 12288 + 255) / 256;
  int nbWl1  = (12288 + 255) / 256;
  k_prep_all<<<nbNode + nbPack + nbWtf + nbWl1, 256, 0, stream>>>(
      x, W_node, b_node, hA, N, nbNode, W_e2, Bph, nbPack,
      W_ih, W_hh, WpI, WpH, nbWtf, W_l1, Wp1);

  u16* hcur = hA;
  u16* hnxt = hB;
  int gconv = (E + 127) / 128;
  int ngru = (N + 63) / 64;
  for (int it = 0; it < 3; ++it) {
    k_conv_fused<<<gconv, 256, 0, stream>>>(Ahi, Bph, b_e2, hcur, src, pos, msgh, E);
    k_gru_mfma<<<ngru, 256, 0, stream>>>(msgh, row, conv_bias, WpI, WpH,
                                         b_ih, b_hh, hcur, hnxt, N);
    u16* tmp = hcur; hcur = hnxt; hnxt = tmp;
  }
  k_final_mfma<<<(E3 + 63) / 64, 256, 0, stream>>>(hcur, edge_attr3, edge_index3, Wp1,
                                                   b_l1, W_l2, b_l2, (float*)d_out, E3);
}